// Round 6
// baseline (273.510 us; speedup 1.0000x reference)
//
#include <hip/hip_runtime.h>
#include <hip/hip_bf16.h>
#include <cstdint>
#include <cstddef>

#define N_NODES 10000
#define M_PAD   10240   // 80 panels of 128; 80 % 8 == 0 -> panel%8 = XCD under round-robin
#define HEADS   4

typedef __bf16 bfrag8 __attribute__((ext_vector_type(8)));
typedef __bf16 bfrag2 __attribute__((ext_vector_type(2)));
typedef float  floatx4 __attribute__((ext_vector_type(4)));
typedef float  floatx2 __attribute__((ext_vector_type(2)));

#define S0V (M_PAD * 512 / 8)   // xb
#define S1E (512 * 512 / 8)     // W1T
#define S2E (512 * 512 / 8)     // W2T   (done in gemm1s)
#define S3E (512 * 128 / 8)     // W3T   (done in gemm1s)
#define S4E (128 * 256 / 8)     // WlT   (done in gemm1s)
#define S5E (512 * 256 / 8)     // WrT   (done in gemm1s)

// ---------------- prep: x->bf16 pad, W1 transpose, degree count; last block
// runs the CSR scan. NO __threadfence (R4: 400us L2-flush disaster) — deg is
// written/read only via device-scope atomics, so vmcnt drain + done-counter
// (relaxed) is sufficient ordering. ----

__global__ __launch_bounds__(256) void prep(const float* __restrict__ x,
                                            const float* __restrict__ W1,
                                            const int* __restrict__ edst, int E,
                                            __bf16* __restrict__ xb,
                                            __bf16* __restrict__ W1T,
                                            int* __restrict__ deg,
                                            int* __restrict__ rowptr,
                                            int* __restrict__ cursor,
                                            int* __restrict__ donecnt) {
    int i = blockIdx.x * 256 + threadIdx.x;
    if (i < S0V) {
        int base = i * 8;
        int row = base >> 9;
        bfrag8 r = {};
        if (row < N_NODES) {
            float4 f0 = ((const float4*)x)[i * 2];
            float4 f1 = ((const float4*)x)[i * 2 + 1];
            r[0] = (__bf16)f0.x; r[1] = (__bf16)f0.y; r[2] = (__bf16)f0.z; r[3] = (__bf16)f0.w;
            r[4] = (__bf16)f1.x; r[5] = (__bf16)f1.y; r[6] = (__bf16)f1.z; r[7] = (__bf16)f1.w;
        }
        *(bfrag8*)(xb + base) = r;
    } else if ((i -= S0V) < S1E) {          // W1: K=512, N=512
        int n = i & 511, kb = (i >> 9) * 8;
        bfrag8 r;
#pragma unroll
        for (int t = 0; t < 8; ++t) r[t] = (__bf16)W1[(kb + t) * 512 + n];
        *(bfrag8*)(W1T + n * 512 + kb) = r;
    } else if ((i -= S1E) < E) {
        atomicAdd(&deg[edst[i]], 1);
    }

    // ---- last finishing block runs the scan ----
    asm volatile("s_waitcnt vmcnt(0)" ::: "memory");   // own atomics performed
    __syncthreads();                                    // whole block's atomics performed
    __shared__ int amLast;
    if (threadIdx.x == 0) {
        int prev = __hip_atomic_fetch_add(donecnt, 1, __ATOMIC_RELAXED,
                                          __HIP_MEMORY_SCOPE_AGENT);
        amLast = (prev == (int)gridDim.x - 1);
    }
    __syncthreads();
    if (!amLast) return;

    __shared__ int wtot[4], woff[4];
    int t = threadIdx.x, lane = t & 63, wv = t >> 6;
    const int chunk = (N_NODES + 255) / 256;   // 40
    int beg = t * chunk, end = beg + chunk;
    if (end > N_NODES) end = N_NODES;
    if (beg > N_NODES) beg = N_NODES;
    int s = 0;
    for (int j = beg; j < end; ++j)
        s += __hip_atomic_load(&deg[j], __ATOMIC_RELAXED, __HIP_MEMORY_SCOPE_AGENT) + 1;
    int v = s;
#pragma unroll
    for (int off = 1; off < 64; off <<= 1) {
        int o = __shfl_up(v, off);
        if (lane >= off) v += o;
    }
    if (lane == 63) wtot[wv] = v;
    __syncthreads();
    if (t == 0) {
        int r = 0;
#pragma unroll
        for (int w2 = 0; w2 < 4; ++w2) { woff[w2] = r; r += wtot[w2]; }
        rowptr[N_NODES] = r;
    }
    __syncthreads();
    int off = woff[wv] + v - s;
    for (int j = beg; j < end; ++j) {
        rowptr[j] = off; cursor[j] = off;
        off += __hip_atomic_load(&deg[j], __ATOMIC_RELAXED, __HIP_MEMORY_SCOPE_AGENT) + 1;
    }
}

// ---------------- MFMA GEMM K-loop: 2-phase double-buffered (T3-min recipe).
// Stage K-step t+1 into buf^1 while MFMAing step t; ONE barrier per step.
// LDS arena layout (64KB): [A0 16K | B0 16K | A1 16K | B1 16K]; buf stride
// 16384 bf16 elements. Staging dest = wave-uniform base + lane*16B (gload_lds
// constraint, verified layout). ----

template <int NT>
__device__ __forceinline__ void gemm_loop(const __bf16* __restrict__ A,
                                          const __bf16* __restrict__ BT, int K,
                                          int m0, int n0, int wave, int lane,
                                          char* smem, floatx4 (&acc)[2][NT]) {
    __bf16* As = (__bf16*)smem;
    int r = wave * 8 + (lane >> 3);          // 0..31 staging row
    int kof = (lane & 7) * 8;
    const __bf16* gA = A + (size_t)(m0 + r) * K + kof;
    const __bf16* gB = BT + (size_t)(n0 + r) * K + kof;
    const int lof = r * 64 + kof;            // == (wave*512 + lane*8): lane-linear
    const int fAo = (wave * 32 + (lane & 15)) * 64 + (lane >> 4) * 8;
    const int fBo = (lane & 15) * 64 + (lane >> 4) * 8;

    auto stage = [&](int buf) {
        __bf16* dA = As + buf * 16384 + lof;
        __bf16* dB = As + 8192 + buf * 16384 + lof;
#pragma unroll
        for (int u = 0; u < 4; ++u)
            __builtin_amdgcn_global_load_lds(
                (const __attribute__((address_space(1))) void*)(gA + (size_t)u * 32 * K),
                (__attribute__((address_space(3))) void*)(dA + u * 32 * 64), 16, 0, 0);
#pragma unroll
        for (int u = 0; u < NT / 2; ++u)
            __builtin_amdgcn_global_load_lds(
                (const __attribute__((address_space(1))) void*)(gB + (size_t)u * 32 * K),
                (__attribute__((address_space(3))) void*)(dB + u * 32 * 64), 16, 0, 0);
        gA += 64; gB += 64;
    };

    stage(0);
    __syncthreads();                          // compiler drains vmcnt before barrier
    const int nst = K >> 6;
    for (int t = 0; t < nst; ++t) {
        int cur = t & 1;
        if (t + 1 < nst) stage(cur ^ 1);      // prefetch overlaps MFMA below
        const __bf16* fA = As + cur * 16384 + fAo;
        const __bf16* fB = As + 8192 + cur * 16384 + fBo;
#pragma unroll
        for (int ks = 0; ks < 2; ++ks) {
            bfrag8 a0 = *(const bfrag8*)(fA + ks * 32);
            bfrag8 a1 = *(const bfrag8*)(fA + 16 * 64 + ks * 32);
#pragma unroll
            for (int nt = 0; nt < NT; ++nt) {
                bfrag8 b = *(const bfrag8*)(fB + nt * 16 * 64 + ks * 32);
                acc[0][nt] = __builtin_amdgcn_mfma_f32_16x16x32_bf16(a0, b, acc[0][nt], 0, 0, 0);
                acc[1][nt] = __builtin_amdgcn_mfma_f32_16x16x32_bf16(a1, b, acc[1][nt], 0, 0, 0);
            }
        }
        __syncthreads();                      // next-buf staged + reads of cur done
    }
}

// one 128x128 tile of H = A@B^T, fp8 out + fused logit sums (full head per tile)
__device__ __forceinline__ void gemm_h_tile(const __bf16* __restrict__ A,
                                            const __bf16* __restrict__ BT,
                                            unsigned char* __restrict__ C8,
                                            int N, int K, int H,
                                            const float* __restrict__ as_,
                                            const float* __restrict__ ad_,
                                            float* __restrict__ esp,
                                            float* __restrict__ edp,
                                            int t, char* smem,
                                            int wave, int lane) {
    int m0 = (t % 80) * 128, n0 = (t / 80) * 128;
    floatx4 acc[2][8] = {};
    gemm_loop<8>(A, BT, K, m0, n0, wave, lane, smem, acc);

    int crow = m0 + wave * 32 + (lane >> 4) * 4;
    int ccol = n0 + (lane & 15);
#pragma unroll
    for (int mt = 0; mt < 2; ++mt)
#pragma unroll
        for (int nt = 0; nt < 8; ++nt)
#pragma unroll
            for (int r = 0; r < 4; ++r) {
                float v = acc[mt][nt][r];
                size_t o = (size_t)(crow + mt * 16 + r) * N + ccol + nt * 16;
                int p = __builtin_amdgcn_cvt_pk_fp8_f32(v, v, 0, false);
                C8[o] = (unsigned char)(p & 0xff);
            }

    int head = n0 >> 7;
    float a_sv[8], a_dv[8];
#pragma unroll
    for (int nt = 0; nt < 8; ++nt) {
        int cin = nt * 16 + (lane & 15);
        a_sv[nt] = as_[head * 128 + cin];
        a_dv[nt] = ad_[head * 128 + cin];
    }
#pragma unroll
    for (int mt = 0; mt < 2; ++mt)
#pragma unroll
        for (int r = 0; r < 4; ++r) {
            float ps = 0.f, pd = 0.f;
#pragma unroll
            for (int nt = 0; nt < 8; ++nt) {
                float v = acc[mt][nt][r];
                ps += v * a_sv[nt];
                pd += v * a_dv[nt];
            }
#pragma unroll
            for (int off = 8; off; off >>= 1) {
                ps += __shfl_xor(ps, off);
                pd += __shfl_xor(pd, off);
            }
            if ((lane & 15) == 0) {
                int row = crow + mt * 16 + r;
                esp[row * H + head] = ps;
                edp[row * H + head] = pd;
            }
        }
}

// standalone gemm_h (layer 2): grid (80, H)
__global__ __launch_bounds__(256) void gemm_h(const __bf16* __restrict__ A,
                                              const __bf16* __restrict__ BT,
                                              unsigned char* __restrict__ C8,
                                              int N, int K, int H,
                                              const float* __restrict__ as_,
                                              const float* __restrict__ ad_,
                                              float* __restrict__ esp,
                                              float* __restrict__ edp) {
    __shared__ __align__(16) char smem[65536];
    int tid = threadIdx.x, wave = tid >> 6, lane = tid & 63;
    int t = blockIdx.x + 80 * blockIdx.y;
    gemm_h_tile(A, BT, C8, N, K, H, as_, ad_, esp, edp, t, smem, wave, lane);
}

// merged: gemm_h layer 1 (blocks 0..319) + CSR scatter + W2/W3/Wl/Wr transposes
// (consumers launch >=2 dispatches later). All independent of each other.
__global__ __launch_bounds__(256) void gemm1s(const __bf16* __restrict__ A,
                                              const __bf16* __restrict__ BT,
                                              unsigned char* __restrict__ C8,
                                              const float* __restrict__ as_,
                                              const float* __restrict__ ad_,
                                              float* __restrict__ esp,
                                              float* __restrict__ edp,
                                              const int* __restrict__ esrc,
                                              const int* __restrict__ edst, int E,
                                              int* __restrict__ cursor,
                                              int* __restrict__ csr,
                                              const float* __restrict__ W2,
                                              const float* __restrict__ W3,
                                              const float* __restrict__ Wl,
                                              const float* __restrict__ Wr,
                                              __bf16* __restrict__ W2T,
                                              __bf16* __restrict__ W3T,
                                              __bf16* __restrict__ WlT,
                                              __bf16* __restrict__ WrT) {
    __shared__ __align__(16) char smem[65536];
    int bid = blockIdx.x;
    const int scat = (E + N_NODES + 255) >> 8;
    if (bid >= 320 + scat) {                 // weight transposes
        int i = (bid - 320 - scat) * 256 + threadIdx.x;
        if (i < S2E) {                       // W2: K=512, N=512
            int n = i & 511, kb = (i >> 9) * 8;
            bfrag8 r;
#pragma unroll
            for (int t = 0; t < 8; ++t) r[t] = (__bf16)W2[(kb + t) * 512 + n];
            *(bfrag8*)(W2T + n * 512 + kb) = r;
        } else if ((i -= S2E) < S3E) {       // W3: K=512, N=128
            int n = i & 127, kb = (i >> 7) * 8;
            bfrag8 r;
#pragma unroll
            for (int t = 0; t < 8; ++t) r[t] = (__bf16)W3[(kb + t) * 128 + n];
            *(bfrag8*)(W3T + n * 512 + kb) = r;
        } else if ((i -= S3E) < S4E) {       // Wl: K=128, N=256
            int n = i & 255, kb = (i >> 8) * 8;
            bfrag8 r;
#pragma unroll
            for (int t = 0; t < 8; ++t) r[t] = (__bf16)Wl[(kb + t) * 256 + n];
            *(bfrag8*)(WlT + n * 128 + kb) = r;
        } else if ((i -= S4E) < S5E) {       // Wr: K=512, N=256
            int n = i & 255, kb = (i >> 8) * 8;
            bfrag8 r;
#pragma unroll
            for (int t = 0; t < 8; ++t) r[t] = (__bf16)Wr[(kb + t) * 256 + n];
            *(bfrag8*)(WrT + n * 512 + kb) = r;
        }
        return;
    }
    if (bid >= 320) {                        // CSR scatter
        int i = (bid - 320) * 256 + threadIdx.x;
        if (i < E) {
            int pos = atomicAdd(&cursor[edst[i]], 1);
            csr[pos] = esrc[i];
        } else if (i < E + N_NODES) {
            int v = i - E;
            int pos = atomicAdd(&cursor[v], 1);
            csr[pos] = v;                    // self-loop
        }
        return;
    }
    int tid = threadIdx.x, wave = tid >> 6, lane = tid & 63;
    gemm_h_tile(A, BT, C8, 512, 512, 4, as_, ad_, esp, edp, bid, smem, wave, lane);
}

// merged: gemm_h layer 3 (blocks 0..79, H=1 N=128) + residual out = xb@WrT + br
__global__ __launch_bounds__(256) void gemm3r(const __bf16* __restrict__ hb,
                                              const __bf16* __restrict__ W3T,
                                              unsigned char* __restrict__ C8,
                                              const float* __restrict__ a3s,
                                              const float* __restrict__ a3d,
                                              float* __restrict__ esp,
                                              float* __restrict__ edp,
                                              const __bf16* __restrict__ xb,
                                              const __bf16* __restrict__ WrT,
                                              const float* __restrict__ br,
                                              float* __restrict__ out) {
    __shared__ __align__(16) char smem[65536];
    int tid = threadIdx.x, wave = tid >> 6, lane = tid & 63;
    int bid = blockIdx.x;
    if (bid < 80) {
        gemm_h_tile(hb, W3T, C8, 128, 512, 1, a3s, a3d, esp, edp, bid, smem, wave, lane);
        return;
    }
    int t = bid - 80;
    int m0 = (t % 80) * 128, n0 = (t / 80) * 64;
    floatx4 acc[2][4] = {};
    gemm_loop<4>(xb, WrT, 512, m0, n0, wave, lane, smem, acc);

    int crow = m0 + wave * 32 + (lane >> 4) * 4;
    int ccol = n0 + (lane & 15);
#pragma unroll
    for (int mt = 0; mt < 2; ++mt)
#pragma unroll
        for (int nt = 0; nt < 4; ++nt)
#pragma unroll
            for (int r = 0; r < 4; ++r) {
                int row = crow + mt * 16 + r;
                int col = ccol + nt * 16;
                if (row < N_NODES)
                    out[(size_t)row * 256 + col] = acc[mt][nt][r] + br[col];
            }
}

// final accumulate: out += hb3@WlT^T + bl  (K=128 only)
__global__ __launch_bounds__(256) void gemm_acc(const __bf16* __restrict__ hb3,
                                                const __bf16* __restrict__ WlT,
                                                float* __restrict__ out,
                                                const float* __restrict__ bl) {
    __shared__ __align__(16) char smem[65536];
    int tid = threadIdx.x, wave = tid >> 6, lane = tid & 63;
    int m0 = blockIdx.x * 128, n0 = blockIdx.y * 64;
    floatx4 acc[2][4] = {};
    gemm_loop<4>(hb3, WlT, 128, m0, n0, wave, lane, smem, acc);

    int crow = m0 + wave * 32 + (lane >> 4) * 4;
    int ccol = n0 + (lane & 15);
#pragma unroll
    for (int mt = 0; mt < 2; ++mt)
#pragma unroll
        for (int nt = 0; nt < 4; ++nt)
#pragma unroll
            for (int r = 0; r < 4; ++r) {
                int row = crow + mt * 16 + r;
                int col = ccol + nt * 16;
                if (row < N_NODES) {
                    size_t o = (size_t)row * 256 + col;
                    out[o] = out[o] + acc[mt][nt][r] + bl[col];
                }
            }
}

// ---------------- fused softmax + weighted gather, fp8 H (R2-proven) ----------------

template <int H>
__global__ __launch_bounds__(256) void gather_agg(const unsigned char* __restrict__ H8,
                                                  const float* __restrict__ esp,
                                                  const float* __restrict__ edp,
                                                  const int* __restrict__ rowptr,
                                                  const int* __restrict__ csr,
                                                  const float* __restrict__ bias,
                                                  __bf16* __restrict__ outb) {
    constexpr int F = H * 128;
    constexpr int CH = F / 64;          // 8 or 2
    __shared__ int   sIdx[4][64];
    __shared__ float sWgt[4][64 * H];
    int wave = threadIdx.x >> 6, lane = threadIdx.x & 63;
    int node = blockIdx.x * 4 + wave;
    if (node >= M_PAD) return;
    __bf16* op = outb + (size_t)node * F + lane * CH;
    if (node >= N_NODES) {
        if (H == 4) { bfrag8 z = {}; *(bfrag8*)op = z; }
        else        { bfrag2 z = {}; *(bfrag2*)op = z; }
        return;
    }
    int hsel = (H == 4) ? (lane >> 4) : 0;
    const unsigned char* hp = H8 + lane * CH;
    int beg = rowptr[node], end = rowptr[node + 1];
    float acc[CH] = {};
    float wsum = 0.f;

    float edv0 = 0.f, edv1 = 0.f, edv2 = 0.f, edv3 = 0.f;
    if (H == 4) {
        float4 e4 = *(const float4*)(edp + node * 4);
        edv0 = e4.x; edv1 = e4.y; edv2 = e4.z; edv3 = e4.w;
    } else {
        edv0 = edp[node];
    }

    for (int t0 = beg; t0 < end; t0 += 64) {
        int n_t = end - t0; if (n_t > 64) n_t = 64;
        // pass 1: one lane per edge, all H logits once
        if (lane < n_t) {
            int s = csr[t0 + lane];
            sIdx[wave][lane] = s;
            if (H == 4) {
                float4 es = *(const float4*)(esp + s * 4);
                float tt0 = es.x + edv0; tt0 = tt0 > 0.f ? tt0 : 0.2f * tt0;
                float tt1 = es.y + edv1; tt1 = tt1 > 0.f ? tt1 : 0.2f * tt1;
                float tt2 = es.z + edv2; tt2 = tt2 > 0.f ? tt2 : 0.2f * tt2;
                float tt3 = es.w + edv3; tt3 = tt3 > 0.f ? tt3 : 0.2f * tt3;
                floatx4 w4 = { __expf(tt0), __expf(tt1), __expf(tt2), __expf(tt3) };
                *(floatx4*)&sWgt[wave][lane * 4] = w4;
            } else {
                float tt = esp[s] + edv0; tt = tt > 0.f ? tt : 0.2f * tt;
                sWgt[wave][lane] = __expf(tt);
            }
        }
        asm volatile("s_waitcnt lgkmcnt(0)" ::: "memory");

        // pass 2: weighted gather, 4-deep pipelined
        int e = 0;
        for (; e + 3 < n_t; e += 4) {
            int s4[4]; float w4[4];
#pragma unroll
            for (int u = 0; u < 4; ++u) {
                s4[u] = sIdx[wave][e + u];
                w4[u] = sWgt[wave][(e + u) * H + hsel];
            }
            if (H == 4) {
                uint2 p4[4];
#pragma unroll
                for (int u = 0; u < 4; ++u) p4[u] = *(const uint2*)(hp + (size_t)s4[u] * F);
#pragma unroll
                for (int u = 0; u < 4; ++u) {
                    float wgt = w4[u];
                    wsum += wgt;
                    floatx2 f0 = __builtin_amdgcn_cvt_pk_f32_fp8(p4[u].x, false);
                    floatx2 f1 = __builtin_amdgcn_cvt_pk_f32_fp8(p4[u].x, true);
                    floatx2 f2 = __builtin_amdgcn_cvt_pk_f32_fp8(p4[u].y, false);
                    floatx2 f3 = __builtin_amdgcn_cvt_pk_f32_fp8(p4[u].y, true);
                    acc[0] += wgt * f0[0]; acc[1] += wgt * f0[1];
                    acc[2] += wgt * f1[0]; acc[3] += wgt * f1[1];
                    acc[4] += wgt * f2[0]; acc[5] += wgt * f2[1];
                    acc[6] += wgt * f3[0]; acc[7] += wgt * f3[1];
                }
            } else {
                unsigned short p4[4];
#pragma unroll
                for (int u = 0; u < 4; ++u) p4[u] = *(const unsigned short*)(hp + (size_t)s4[u] * F);
#pragma unroll
                for (int u = 0; u < 4; ++u) {
                    float wgt = w4[u];
                    wsum += wgt;
                    floatx2 f0 = __builtin_amdgcn_cvt_pk_f32_fp8((int)p4[u], false);
                    acc[0] += wgt * f0[0]; acc[1] += wgt * f0[1];
                }
            }
        }
        for (; e < n_t; ++e) {
            int s0 = sIdx[wave][e];
            float wgt = sWgt[wave][e * H + hsel];
            wsum += wgt;
            if (H == 4) {
                uint2 p = *(const uint2*)(hp + (size_t)s0 * F);
                floatx2 f0 = __builtin_amdgcn_cvt_pk_f32_fp8(p.x, false);
                floatx2 f1 = __builtin_amdgcn_cvt_pk_f32_fp8(p.x, true);
                floatx2 f2 = __builtin_amdgcn_cvt_pk_f32_fp8(p.y, false);
                floatx2 f3 = __builtin_amdgcn_cvt_pk_f32_fp8(p.y, true);
                acc[0] += wgt * f0[0]; acc[1] += wgt * f0[1];
                acc[2] += wgt * f1[0]; acc[3] += wgt * f1[1];
                acc[4] += wgt * f2[0]; acc[5] += wgt * f2[1];
                acc[6] += wgt * f3[0]; acc[7] += wgt * f3[1];
            } else {
                unsigned short p = *(const unsigned short*)(hp + (size_t)s0 * F);
                floatx2 f0 = __builtin_amdgcn_cvt_pk_f32_fp8((int)p, false);
                acc[0] += wgt * f0[0]; acc[1] += wgt * f0[1];
            }
        }
    }

    float inv = 1.f / (wsum + 1e-16f);
    if (H == 4) {
        bfrag8 r;
#pragma unroll
        for (int k = 0; k < 8; ++k) {
            float o = acc[k] * inv + bias[lane * 8 + k];
            o = o > 0.f ? o : __expf(o) - 1.f;     // ELU
            r[k] = (__bf16)o;
        }
        *(bfrag8*)op = r;
    } else {
        bfrag2 r;
#pragma unroll
        for (int k = 0; k < 2; ++k) {
            float o = acc[k] * inv + bias[lane * 2 + k];
            o = o > 0.f ? o : __expf(o) - 1.f;
            r[k] = (__bf16)o;
        }
        *(bfrag2*)op = r;
    }
}

// ---------------- launch ----------------

extern "C" void kernel_launch(void* const* d_in, const int* in_sizes, int n_in,
                              void* d_out, int out_size, void* d_ws, size_t ws_size,
                              hipStream_t stream) {
    const float* x   = (const float*)d_in[0];
    const float* W1  = (const float*)d_in[1];
    const float* a1s = (const float*)d_in[2];
    const float* a1d = (const float*)d_in[3];
    const float* b1  = (const float*)d_in[4];
    const float* W2  = (const float*)d_in[5];
    const float* a2s = (const float*)d_in[6];
    const float* a2d = (const float*)d_in[7];
    const float* b2  = (const float*)d_in[8];
    const float* W3  = (const float*)d_in[9];
    const float* a3s = (const float*)d_in[10];
    const float* a3d = (const float*)d_in[11];
    const float* b3  = (const float*)d_in[12];
    const float* Wl  = (const float*)d_in[13];
    const float* bl  = (const float*)d_in[14];
    const float* Wr  = (const float*)d_in[15];
    const float* br  = (const float*)d_in[16];
    const int*   ei  = (const int*)d_in[17];
    const int E = in_sizes[17] / 2;
    const int* esrc = ei;
    const int* edst = ei + E;
    const int slots = E + N_NODES;
    float* out = (float*)d_out;

    char* w = (char*)d_ws;
    auto alloc = [&](size_t b) { char* p = w; w += (b + 255) & ~(size_t)255; return p; };
    __bf16* xb  = (__bf16*)alloc((size_t)M_PAD * 512 * 2);
    __bf16* hb  = (__bf16*)alloc((size_t)M_PAD * 512 * 2);
    __bf16* hb3 = (__bf16*)alloc((size_t)M_PAD * 128 * 2);
    unsigned char* Hi8 = (unsigned char*)alloc((size_t)M_PAD * 512);
    __bf16* W1T = (__bf16*)alloc(512 * 512 * 2);
    __bf16* W2T = (__bf16*)alloc(512 * 512 * 2);
    __bf16* W3T = (__bf16*)alloc(128 * 512 * 2);
    __bf16* WlT = (__bf16*)alloc(256 * 128 * 2);
    __bf16* WrT = (__bf16*)alloc(256 * 512 * 2);
    float* esp    = (float*)alloc((size_t)M_PAD * HEADS * 4);
    float* edp    = (float*)alloc((size_t)M_PAD * HEADS * 4);
    int*   deg    = (int*)alloc((N_NODES + 1) * 4);    // +1: donecnt
    int*   rowptr = (int*)alloc((N_NODES + 1) * 4);
    int*   cursor = (int*)alloc(N_NODES * 4);
    int*   csr    = (int*)alloc((size_t)slots * 4);

    (void)hipMemsetAsync(deg, 0, (N_NODES + 1) * sizeof(int), stream);

    // prep (xb + W1T + deg count + last-block CSR scan)
    const int prep_total = S0V + S1E + E;
    prep<<<(prep_total + 255) / 256, 256, 0, stream>>>(x, W1, edst, E, xb, W1T,
                                                       deg, rowptr, cursor,
                                                       deg + N_NODES);

    const int scat_blocks = (E + N_NODES + 255) / 256;
    const int tr_blocks = (S2E + S3E + S4E + S5E) / 256;   // 240
    // layer 1 GEMM + CSR scatter + 4 weight transposes (one dispatch)
    gemm1s<<<320 + scat_blocks + tr_blocks, 256, 0, stream>>>(
        xb, W1T, Hi8, a1s, a1d, esp, edp, esrc, edst, E, cursor, csr,
        W2, W3, Wl, Wr, W2T, W3T, WlT, WrT);
    gather_agg<4><<<M_PAD / 4, 256, 0, stream>>>(Hi8, esp, edp, rowptr, csr, b1, hb);
    // layer 2
    gemm_h<<<dim3(80, 4), 256, 0, stream>>>(hb, W2T, Hi8, 512, 512, 4,
                                            a2s, a2d, esp, edp);
    gather_agg<4><<<M_PAD / 4, 256, 0, stream>>>(Hi8, esp, edp, rowptr, csr, b2, hb);
    // layer 3 (H=1) + residual out = xb@WrT + br (one dispatch)
    gemm3r<<<400, 256, 0, stream>>>(hb, W3T, Hi8, a3s, a3d, esp, edp,
                                    xb, WrT, br, out);
    gather_agg<1><<<M_PAD / 4, 256, 0, stream>>>(Hi8, esp, edp, rowptr, csr, b3, hb3);
    // final: out += hb3@WlT + bl (K=128)
    gemm_acc<<<dim3(80, 4), 256, 0, stream>>>(hb3, WlT, out, bl);
}

// Round 7
// 262.565 us; speedup vs baseline: 1.0417x; 1.0417x over previous
//
#include <hip/hip_runtime.h>
#include <hip/hip_bf16.h>
#include <cstdint>
#include <cstddef>

#define N_NODES 10000
#define M_PAD   10240   // 80 panels of 128; 80 % 8 == 0 -> panel%8 = XCD under round-robin
#define HEADS   4

typedef __bf16 bfrag8 __attribute__((ext_vector_type(8)));
typedef __bf16 bfrag2 __attribute__((ext_vector_type(2)));
typedef float  floatx4 __attribute__((ext_vector_type(4)));
typedef float  floatx2 __attribute__((ext_vector_type(2)));

#define S0V (M_PAD * 512 / 8)   // xb
#define S1E (512 * 512 / 8)     // W1T
#define S2E (512 * 512 / 8)     // W2T
#define S3E (512 * 128 / 8)     // W3T
#define S5E (512 * 256 / 8)     // WrT   (Wl is consumed untransposed by gather3)

// ---------------- prep: x->bf16 pad, 4 weight transposes, degree count.
// NO tail work (R4/R6 lesson: in-kernel completion protocols cost 30-400us). ----

__global__ __launch_bounds__(256) void prep(const float* __restrict__ x,
                                            const float* __restrict__ W1,
                                            const float* __restrict__ W2,
                                            const float* __restrict__ W3,
                                            const float* __restrict__ Wr,
                                            const int* __restrict__ edst, int E,
                                            __bf16* __restrict__ xb,
                                            __bf16* __restrict__ W1T,
                                            __bf16* __restrict__ W2T,
                                            __bf16* __restrict__ W3T,
                                            __bf16* __restrict__ WrT,
                                            int* __restrict__ deg) {
    int i = blockIdx.x * 256 + threadIdx.x;
    if (i < S0V) {
        int base = i * 8;
        int row = base >> 9;
        bfrag8 r = {};
        if (row < N_NODES) {
            float4 f0 = ((const float4*)x)[i * 2];
            float4 f1 = ((const float4*)x)[i * 2 + 1];
            r[0] = (__bf16)f0.x; r[1] = (__bf16)f0.y; r[2] = (__bf16)f0.z; r[3] = (__bf16)f0.w;
            r[4] = (__bf16)f1.x; r[5] = (__bf16)f1.y; r[6] = (__bf16)f1.z; r[7] = (__bf16)f1.w;
        }
        *(bfrag8*)(xb + base) = r;
    } else if ((i -= S0V) < S1E) {          // W1: K=512, N=512
        int n = i & 511, kb = (i >> 9) * 8;
        bfrag8 r;
#pragma unroll
        for (int t = 0; t < 8; ++t) r[t] = (__bf16)W1[(kb + t) * 512 + n];
        *(bfrag8*)(W1T + n * 512 + kb) = r;
    } else if ((i -= S1E) < S2E) {          // W2
        int n = i & 511, kb = (i >> 9) * 8;
        bfrag8 r;
#pragma unroll
        for (int t = 0; t < 8; ++t) r[t] = (__bf16)W2[(kb + t) * 512 + n];
        *(bfrag8*)(W2T + n * 512 + kb) = r;
    } else if ((i -= S2E) < S3E) {          // W3: K=512, N=128
        int n = i & 127, kb = (i >> 7) * 8;
        bfrag8 r;
#pragma unroll
        for (int t = 0; t < 8; ++t) r[t] = (__bf16)W3[(kb + t) * 128 + n];
        *(bfrag8*)(W3T + n * 512 + kb) = r;
    } else if ((i -= S3E) < S5E) {          // Wr: K=512, N=256
        int n = i & 255, kb = (i >> 8) * 8;
        bfrag8 r;
#pragma unroll
        for (int t = 0; t < 8; ++t) r[t] = (__bf16)Wr[(kb + t) * 256 + n];
        *(bfrag8*)(WrT + n * 512 + kb) = r;
    } else if ((i -= S5E) < E) {
        atomicAdd(&deg[edst[i]], 1);
    }
}

// ---------------- CSR scan: 1024 threads, chunk=10 rows/thread (R2-proven) ----

__global__ __launch_bounds__(1024) void scan_kernel(const int* __restrict__ deg,
                                                    int* __restrict__ rowptr,
                                                    int* __restrict__ cursor, int n) {
    __shared__ int wtot[16], woff[16];
    int t = threadIdx.x, lane = t & 63, wv = t >> 6;
    int chunk = (n + 1023) / 1024;
    int beg = t * chunk, end = beg + chunk; if (end > n) end = n; if (beg > n) beg = n;
    int s = 0;
    for (int i = beg; i < end; ++i) s += deg[i] + 1;   // +1 self-loop
    int v = s;
#pragma unroll
    for (int off = 1; off < 64; off <<= 1) {
        int o = __shfl_up(v, off);
        if (lane >= off) v += o;
    }
    if (lane == 63) wtot[wv] = v;
    __syncthreads();
    if (t == 0) {
        int r = 0;
#pragma unroll
        for (int i = 0; i < 16; ++i) { woff[i] = r; r += wtot[i]; }
        rowptr[n] = r;
    }
    __syncthreads();
    int off = woff[wv] + v - s;     // exclusive prefix
    for (int i = beg; i < end; ++i) {
        rowptr[i] = off; cursor[i] = off;
        off += deg[i] + 1;
    }
}

// ---------------- MFMA GEMM K-loop, BK=64, tile 128(M) x 16*NT(N) (R5-proven) ----

template <int NT>
__device__ __forceinline__ void gemm_loop(const __bf16* __restrict__ A,
                                          const __bf16* __restrict__ BT, int K,
                                          int m0, int n0, int wave, int lane,
                                          __bf16* As, __bf16* Bs,
                                          floatx4 (&acc)[2][NT]) {
    int r = wave * 8 + (lane >> 3);          // 0..31 staging row
    int kof = (lane & 7) * 8;
    const __bf16* gA = A + (size_t)(m0 + r) * K + kof;
    const __bf16* gB = BT + (size_t)(n0 + r) * K + kof;
    __bf16* lA = As + r * 64 + kof;
    __bf16* lB = Bs + r * 64 + kof;
    const __bf16* fA = As + (wave * 32 + (lane & 15)) * 64 + (lane >> 4) * 8;
    const __bf16* fB = Bs + (lane & 15) * 64 + (lane >> 4) * 8;

    for (int k0 = 0; k0 < K; k0 += 64) {
#pragma unroll
        for (int u = 0; u < 4; ++u)
            __builtin_amdgcn_global_load_lds(
                (const __attribute__((address_space(1))) void*)(gA + (size_t)u * 32 * K),
                (__attribute__((address_space(3))) void*)(lA + u * 32 * 64), 16, 0, 0);
#pragma unroll
        for (int u = 0; u < NT / 2; ++u)
            __builtin_amdgcn_global_load_lds(
                (const __attribute__((address_space(1))) void*)(gB + (size_t)u * 32 * K),
                (__attribute__((address_space(3))) void*)(lB + u * 32 * 64), 16, 0, 0);
        gA += 64; gB += 64;
        __syncthreads();

#pragma unroll
        for (int ks = 0; ks < 2; ++ks) {
            bfrag8 a0 = *(const bfrag8*)(fA + ks * 32);
            bfrag8 a1 = *(const bfrag8*)(fA + 16 * 64 + ks * 32);
#pragma unroll
            for (int nt = 0; nt < NT; ++nt) {
                bfrag8 b = *(const bfrag8*)(fB + nt * 16 * 64 + ks * 32);
                acc[0][nt] = __builtin_amdgcn_mfma_f32_16x16x32_bf16(a0, b, acc[0][nt], 0, 0, 0);
                acc[1][nt] = __builtin_amdgcn_mfma_f32_16x16x32_bf16(a1, b, acc[1][nt], 0, 0, 0);
            }
        }
        __syncthreads();
    }
}

// one 128x128 tile of H = A@B^T, fp8 out + fused logit sums (full head per tile)
__device__ __forceinline__ void gemm_h_tile(const __bf16* __restrict__ A,
                                            const __bf16* __restrict__ BT,
                                            unsigned char* __restrict__ C8,
                                            int N, int K, int H,
                                            const float* __restrict__ as_,
                                            const float* __restrict__ ad_,
                                            float* __restrict__ esp,
                                            float* __restrict__ edp,
                                            int t, __bf16* As, __bf16* Bs,
                                            int wave, int lane) {
    int m0 = (t % 80) * 128, n0 = (t / 80) * 128;
    floatx4 acc[2][8] = {};
    gemm_loop<8>(A, BT, K, m0, n0, wave, lane, As, Bs, acc);

    int crow = m0 + wave * 32 + (lane >> 4) * 4;
    int ccol = n0 + (lane & 15);
#pragma unroll
    for (int mt = 0; mt < 2; ++mt)
#pragma unroll
        for (int nt = 0; nt < 8; ++nt)
#pragma unroll
            for (int r = 0; r < 4; ++r) {
                float v = acc[mt][nt][r];
                size_t o = (size_t)(crow + mt * 16 + r) * N + ccol + nt * 16;
                int p = __builtin_amdgcn_cvt_pk_fp8_f32(v, v, 0, false);
                C8[o] = (unsigned char)(p & 0xff);
            }

    int head = n0 >> 7;
    float a_sv[8], a_dv[8];
#pragma unroll
    for (int nt = 0; nt < 8; ++nt) {
        int cin = nt * 16 + (lane & 15);
        a_sv[nt] = as_[head * 128 + cin];
        a_dv[nt] = ad_[head * 128 + cin];
    }
#pragma unroll
    for (int mt = 0; mt < 2; ++mt)
#pragma unroll
        for (int r = 0; r < 4; ++r) {
            float ps = 0.f, pd = 0.f;
#pragma unroll
            for (int nt = 0; nt < 8; ++nt) {
                float v = acc[mt][nt][r];
                ps += v * a_sv[nt];
                pd += v * a_dv[nt];
            }
#pragma unroll
            for (int off = 8; off; off >>= 1) {
                ps += __shfl_xor(ps, off);
                pd += __shfl_xor(pd, off);
            }
            if ((lane & 15) == 0) {
                int row = crow + mt * 16 + r;
                esp[row * H + head] = ps;
                edp[row * H + head] = pd;
            }
        }
}

// standalone gemm_h (layer 2): grid (80, H)
__global__ __launch_bounds__(256) void gemm_h(const __bf16* __restrict__ A,
                                              const __bf16* __restrict__ BT,
                                              unsigned char* __restrict__ C8,
                                              int N, int K, int H,
                                              const float* __restrict__ as_,
                                              const float* __restrict__ ad_,
                                              float* __restrict__ esp,
                                              float* __restrict__ edp) {
    __shared__ __align__(16) __bf16 As[128 * 64];
    __shared__ __align__(16) __bf16 Bs[128 * 64];
    int tid = threadIdx.x, wave = tid >> 6, lane = tid & 63;
    int t = blockIdx.x + 80 * blockIdx.y;
    gemm_h_tile(A, BT, C8, N, K, H, as_, ad_, esp, edp, t, As, Bs, wave, lane);
}

// merged: gemm_h layer 1 (blocks 0..319) + CSR scatter (blocks >= 320).
__global__ __launch_bounds__(256) void gemm1s(const __bf16* __restrict__ A,
                                              const __bf16* __restrict__ BT,
                                              unsigned char* __restrict__ C8,
                                              const float* __restrict__ as_,
                                              const float* __restrict__ ad_,
                                              float* __restrict__ esp,
                                              float* __restrict__ edp,
                                              const int* __restrict__ esrc,
                                              const int* __restrict__ edst, int E,
                                              int* __restrict__ cursor,
                                              int* __restrict__ csr) {
    __shared__ __align__(16) __bf16 As[128 * 64];
    __shared__ __align__(16) __bf16 Bs[128 * 64];
    int bid = blockIdx.x;
    if (bid >= 320) {
        int i = (bid - 320) * 256 + threadIdx.x;
        if (i < E) {
            int pos = atomicAdd(&cursor[edst[i]], 1);
            csr[pos] = esrc[i];
        } else if (i < E + N_NODES) {
            int v = i - E;
            int pos = atomicAdd(&cursor[v], 1);
            csr[pos] = v;                              // self-loop
        }
        return;
    }
    int tid = threadIdx.x, wave = tid >> 6, lane = tid & 63;
    gemm_h_tile(A, BT, C8, 512, 512, 4, as_, ad_, esp, edp, bid, As, Bs, wave, lane);
}

// merged: gemm_h layer 3 (blocks 0..79, H=1 N=128) + residual out = xb@WrT + br
__global__ __launch_bounds__(256) void gemm3r(const __bf16* __restrict__ hb,
                                              const __bf16* __restrict__ W3T,
                                              unsigned char* __restrict__ C8,
                                              const float* __restrict__ a3s,
                                              const float* __restrict__ a3d,
                                              float* __restrict__ esp,
                                              float* __restrict__ edp,
                                              const __bf16* __restrict__ xb,
                                              const __bf16* __restrict__ WrT,
                                              const float* __restrict__ br,
                                              float* __restrict__ out) {
    __shared__ __align__(16) __bf16 As[128 * 64];
    __shared__ __align__(16) __bf16 Bs[128 * 64];
    int tid = threadIdx.x, wave = tid >> 6, lane = tid & 63;
    int bid = blockIdx.x;
    if (bid < 80) {
        gemm_h_tile(hb, W3T, C8, 128, 512, 1, a3s, a3d, esp, edp, bid, As, Bs, wave, lane);
        return;
    }
    int t = bid - 80;
    int m0 = (t % 80) * 128, n0 = (t / 80) * 64;
    floatx4 acc[2][4] = {};
    gemm_loop<4>(xb, WrT, 512, m0, n0, wave, lane, As, Bs, acc);

    int crow = m0 + wave * 32 + (lane >> 4) * 4;
    int ccol = n0 + (lane & 15);
#pragma unroll
    for (int mt = 0; mt < 2; ++mt)
#pragma unroll
        for (int nt = 0; nt < 4; ++nt)
#pragma unroll
            for (int r = 0; r < 4; ++r) {
                int row = crow + mt * 16 + r;
                int col = ccol + nt * 16;
                if (row < N_NODES)
                    out[(size_t)row * 256 + col] = acc[mt][nt][r] + br[col];
            }
}

// ---------------- fused softmax + weighted gather, fp8 H ----------------
// H==4: writes bf16 hidden (hb). H==1: folds the FINAL LINEAR — after computing
// the node's 128-wide ELU'd h3 row, stash in LDS and compute out[node] +=
// h3 @ Wl + bl directly (Wl untransposed, coalesced float4 rows, L2-resident).
// Kills the gemm_acc dispatch + hb3 round-trip.

template <int H>
__global__ __launch_bounds__(256) void gather_agg(const unsigned char* __restrict__ H8,
                                                  const float* __restrict__ esp,
                                                  const float* __restrict__ edp,
                                                  const int* __restrict__ rowptr,
                                                  const int* __restrict__ csr,
                                                  const float* __restrict__ bias,
                                                  __bf16* __restrict__ outb,
                                                  const float* __restrict__ Wl,
                                                  const float* __restrict__ bl,
                                                  float* __restrict__ outf) {
    constexpr int F = H * 128;
    constexpr int CH = F / 64;          // 8 or 2
    __shared__ int   sIdx[4][64];
    __shared__ float sWgt[4][64 * H];
    __shared__ float sH3[4][128];       // used by H==1 epilogue only
    int wave = threadIdx.x >> 6, lane = threadIdx.x & 63;
    int node = blockIdx.x * 4 + wave;
    if (node >= M_PAD) return;
    if (node >= N_NODES) {
        if (H == 4) {                       // pad rows feed layer-2/3 GEMMs: zero them
            bfrag8 z = {};
            *(bfrag8*)(outb + (size_t)node * F + lane * CH) = z;
        }
        return;                             // H==1: no output row for pad nodes
    }
    int hsel = (H == 4) ? (lane >> 4) : 0;
    const unsigned char* hp = H8 + lane * CH;
    int beg = rowptr[node], end = rowptr[node + 1];
    float acc[CH] = {};
    float wsum = 0.f;

    float edv0 = 0.f, edv1 = 0.f, edv2 = 0.f, edv3 = 0.f;
    if (H == 4) {
        float4 e4 = *(const float4*)(edp + node * 4);
        edv0 = e4.x; edv1 = e4.y; edv2 = e4.z; edv3 = e4.w;
    } else {
        edv0 = edp[node];
    }

    for (int t0 = beg; t0 < end; t0 += 64) {
        int n_t = end - t0; if (n_t > 64) n_t = 64;
        // pass 1: one lane per edge, all H logits once
        if (lane < n_t) {
            int s = csr[t0 + lane];
            sIdx[wave][lane] = s;
            if (H == 4) {
                float4 es = *(const float4*)(esp + s * 4);
                float tt0 = es.x + edv0; tt0 = tt0 > 0.f ? tt0 : 0.2f * tt0;
                float tt1 = es.y + edv1; tt1 = tt1 > 0.f ? tt1 : 0.2f * tt1;
                float tt2 = es.z + edv2; tt2 = tt2 > 0.f ? tt2 : 0.2f * tt2;
                float tt3 = es.w + edv3; tt3 = tt3 > 0.f ? tt3 : 0.2f * tt3;
                floatx4 w4 = { __expf(tt0), __expf(tt1), __expf(tt2), __expf(tt3) };
                *(floatx4*)&sWgt[wave][lane * 4] = w4;
            } else {
                float tt = esp[s] + edv0; tt = tt > 0.f ? tt : 0.2f * tt;
                sWgt[wave][lane] = __expf(tt);
            }
        }
        asm volatile("s_waitcnt lgkmcnt(0)" ::: "memory");

        // pass 2: weighted gather, 4-deep pipelined
        int e = 0;
        for (; e + 3 < n_t; e += 4) {
            int s4[4]; float w4[4];
#pragma unroll
            for (int u = 0; u < 4; ++u) {
                s4[u] = sIdx[wave][e + u];
                w4[u] = sWgt[wave][(e + u) * H + hsel];
            }
            if (H == 4) {
                uint2 p4[4];
#pragma unroll
                for (int u = 0; u < 4; ++u) p4[u] = *(const uint2*)(hp + (size_t)s4[u] * F);
#pragma unroll
                for (int u = 0; u < 4; ++u) {
                    float wgt = w4[u];
                    wsum += wgt;
                    floatx2 f0 = __builtin_amdgcn_cvt_pk_f32_fp8(p4[u].x, false);
                    floatx2 f1 = __builtin_amdgcn_cvt_pk_f32_fp8(p4[u].x, true);
                    floatx2 f2 = __builtin_amdgcn_cvt_pk_f32_fp8(p4[u].y, false);
                    floatx2 f3 = __builtin_amdgcn_cvt_pk_f32_fp8(p4[u].y, true);
                    acc[0] += wgt * f0[0]; acc[1] += wgt * f0[1];
                    acc[2] += wgt * f1[0]; acc[3] += wgt * f1[1];
                    acc[4] += wgt * f2[0]; acc[5] += wgt * f2[1];
                    acc[6] += wgt * f3[0]; acc[7] += wgt * f3[1];
                }
            } else {
                unsigned short p4[4];
#pragma unroll
                for (int u = 0; u < 4; ++u) p4[u] = *(const unsigned short*)(hp + (size_t)s4[u] * F);
#pragma unroll
                for (int u = 0; u < 4; ++u) {
                    float wgt = w4[u];
                    wsum += wgt;
                    floatx2 f0 = __builtin_amdgcn_cvt_pk_f32_fp8((int)p4[u], false);
                    acc[0] += wgt * f0[0]; acc[1] += wgt * f0[1];
                }
            }
        }
        for (; e < n_t; ++e) {
            int s0 = sIdx[wave][e];
            float wgt = sWgt[wave][e * H + hsel];
            wsum += wgt;
            if (H == 4) {
                uint2 p = *(const uint2*)(hp + (size_t)s0 * F);
                floatx2 f0 = __builtin_amdgcn_cvt_pk_f32_fp8(p.x, false);
                floatx2 f1 = __builtin_amdgcn_cvt_pk_f32_fp8(p.x, true);
                floatx2 f2 = __builtin_amdgcn_cvt_pk_f32_fp8(p.y, false);
                floatx2 f3 = __builtin_amdgcn_cvt_pk_f32_fp8(p.y, true);
                acc[0] += wgt * f0[0]; acc[1] += wgt * f0[1];
                acc[2] += wgt * f1[0]; acc[3] += wgt * f1[1];
                acc[4] += wgt * f2[0]; acc[5] += wgt * f2[1];
                acc[6] += wgt * f3[0]; acc[7] += wgt * f3[1];
            } else {
                unsigned short p = *(const unsigned short*)(hp + (size_t)s0 * F);
                floatx2 f0 = __builtin_amdgcn_cvt_pk_f32_fp8((int)p, false);
                acc[0] += wgt * f0[0]; acc[1] += wgt * f0[1];
            }
        }
    }

    float inv = 1.f / (wsum + 1e-16f);
    if (H == 4) {
        bfrag8 r;
#pragma unroll
        for (int k = 0; k < 8; ++k) {
            float o = acc[k] * inv + bias[lane * 8 + k];
            o = o > 0.f ? o : __expf(o) - 1.f;     // ELU
            r[k] = (__bf16)o;
        }
        *(bfrag8*)(outb + (size_t)node * F + lane * CH) = r;
    } else {
        // ---- fold final linear: out[node] += elu(h3) @ Wl + bl ----
        float o0 = acc[0] * inv + bias[lane * 2];
        float o1 = acc[1] * inv + bias[lane * 2 + 1];
        o0 = o0 > 0.f ? o0 : __expf(o0) - 1.f;
        o1 = o1 > 0.f ? o1 : __expf(o1) - 1.f;
        sH3[wave][lane * 2]     = o0;
        sH3[wave][lane * 2 + 1] = o1;
        asm volatile("s_waitcnt lgkmcnt(0)" ::: "memory");   // same-wave LDS fence

        float4 a = *(const float4*)(bl + lane * 4);          // 4 output cols per lane
        const float* wp = Wl + lane * 4;
#pragma unroll 4
        for (int k = 0; k < 128; ++k) {
            float h = sH3[wave][k];                          // LDS broadcast
            float4 wl = *(const float4*)(wp + k * 256);      // coalesced across lanes
            a.x += h * wl.x; a.y += h * wl.y; a.z += h * wl.z; a.w += h * wl.w;
        }
        float4* op = (float4*)(outf + (size_t)node * 256 + lane * 4);
        float4 cur = *op;                                    // residual from gemm3r
        cur.x += a.x; cur.y += a.y; cur.z += a.z; cur.w += a.w;
        *op = cur;
    }
}

// ---------------- launch ----------------

extern "C" void kernel_launch(void* const* d_in, const int* in_sizes, int n_in,
                              void* d_out, int out_size, void* d_ws, size_t ws_size,
                              hipStream_t stream) {
    const float* x   = (const float*)d_in[0];
    const float* W1  = (const float*)d_in[1];
    const float* a1s = (const float*)d_in[2];
    const float* a1d = (const float*)d_in[3];
    const float* b1  = (const float*)d_in[4];
    const float* W2  = (const float*)d_in[5];
    const float* a2s = (const float*)d_in[6];
    const float* a2d = (const float*)d_in[7];
    const float* b2  = (const float*)d_in[8];
    const float* W3  = (const float*)d_in[9];
    const float* a3s = (const float*)d_in[10];
    const float* a3d = (const float*)d_in[11];
    const float* b3  = (const float*)d_in[12];
    const float* Wl  = (const float*)d_in[13];
    const float* bl  = (const float*)d_in[14];
    const float* Wr  = (const float*)d_in[15];
    const float* br  = (const float*)d_in[16];
    const int*   ei  = (const int*)d_in[17];
    const int E = in_sizes[17] / 2;
    const int* esrc = ei;
    const int* edst = ei + E;
    const int slots = E + N_NODES;
    float* out = (float*)d_out;

    char* w = (char*)d_ws;
    auto alloc = [&](size_t b) { char* p = w; w += (b + 255) & ~(size_t)255; return p; };
    __bf16* xb  = (__bf16*)alloc((size_t)M_PAD * 512 * 2);
    __bf16* hb  = (__bf16*)alloc((size_t)M_PAD * 512 * 2);
    unsigned char* Hi8 = (unsigned char*)alloc((size_t)M_PAD * 512);
    __bf16* W1T = (__bf16*)alloc(512 * 512 * 2);
    __bf16* W2T = (__bf16*)alloc(512 * 512 * 2);
    __bf16* W3T = (__bf16*)alloc(128 * 512 * 2);
    __bf16* WrT = (__bf16*)alloc(256 * 512 * 2);
    float* esp    = (float*)alloc((size_t)M_PAD * HEADS * 4);
    float* edp    = (float*)alloc((size_t)M_PAD * HEADS * 4);
    int*   deg    = (int*)alloc(N_NODES * 4);
    int*   rowptr = (int*)alloc((N_NODES + 1) * 4);
    int*   cursor = (int*)alloc(N_NODES * 4);
    int*   csr    = (int*)alloc((size_t)slots * 4);

    (void)hipMemsetAsync(deg, 0, N_NODES * sizeof(int), stream);

    const int sp_total = S0V + S1E + S2E + S3E + S5E + E;
    prep<<<(sp_total + 255) / 256, 256, 0, stream>>>(x, W1, W2, W3, Wr, edst, E,
                                                     xb, W1T, W2T, W3T, WrT, deg);
    scan_kernel<<<1, 1024, 0, stream>>>(deg, rowptr, cursor, N_NODES);

    const int scat_blocks = (E + N_NODES + 255) / 256;
    // layer 1 GEMM + CSR scatter (one dispatch)
    gemm1s<<<320 + scat_blocks, 256, 0, stream>>>(xb, W1T, Hi8, a1s, a1d, esp, edp,
                                                  esrc, edst, E, cursor, csr);
    gather_agg<4><<<M_PAD / 4, 256, 0, stream>>>(Hi8, esp, edp, rowptr, csr, b1, hb,
                                                 nullptr, nullptr, nullptr);
    // layer 2
    gemm_h<<<dim3(80, 4), 256, 0, stream>>>(hb, W2T, Hi8, 512, 512, 4,
                                            a2s, a2d, esp, edp);
    gather_agg<4><<<M_PAD / 4, 256, 0, stream>>>(Hi8, esp, edp, rowptr, csr, b2, hb,
                                                 nullptr, nullptr, nullptr);
    // layer 3 (H=1) + residual out = xb@WrT + br (one dispatch)
    gemm3r<<<400, 256, 0, stream>>>(hb, W3T, Hi8, a3s, a3d, esp, edp,
                                    xb, WrT, br, out);
    // gather layer 3 + FINAL LINEAR folded (out += elu(h3)@Wl + bl)
    gather_agg<1><<<M_PAD / 4, 256, 0, stream>>>(Hi8, esp, edp, rowptr, csr, b3,
                                                 nullptr, Wl, bl, out);
}

// Round 8
// 248.299 us; speedup vs baseline: 1.1015x; 1.0575x over previous
//
#include <hip/hip_runtime.h>
#include <hip/hip_bf16.h>
#include <cstdint>
#include <cstddef>

#define N_NODES 10000
#define M_PAD   10240   // 80 panels of 128; 80 % 8 == 0 -> panel%8 = XCD under round-robin
#define HEADS   4

typedef __bf16 bfrag8 __attribute__((ext_vector_type(8)));
typedef __bf16 bfrag2 __attribute__((ext_vector_type(2)));
typedef float  floatx4 __attribute__((ext_vector_type(4)));
typedef float  floatx2 __attribute__((ext_vector_type(2)));

#define S0V (M_PAD * 512 / 8)   // xb
#define S1E (512 * 512 / 8)     // W1T
#define S2E (512 * 512 / 8)     // W2T
#define S3E (512 * 128 / 8)     // W3T
#define S4E (128 * 256 / 8)     // WlT
#define S5E (512 * 256 / 8)     // WrT

// ---------------- deg count: tiny standalone kernel BEFORE prep, so prep's
// scan block can read completed deg[] (kernel-boundary ordering — no in-kernel
// completion protocol; R4/R6 lesson). ----

__global__ __launch_bounds__(256) void deg_count(const int* __restrict__ edst, int E,
                                                 int* __restrict__ deg) {
    int i = blockIdx.x * 256 + threadIdx.x;
    if (i < E) atomicAdd(&deg[edst[i]], 1);
}

// ---------------- prep: x->bf16 pad, 5 weight transposes; LAST block does the
// CSR scan (deg complete from deg_count; runs concurrent with other blocks). ----

__global__ __launch_bounds__(256) void prep(const float* __restrict__ x,
                                            const float* __restrict__ W1,
                                            const float* __restrict__ W2,
                                            const float* __restrict__ W3,
                                            const float* __restrict__ Wl,
                                            const float* __restrict__ Wr,
                                            __bf16* __restrict__ xb,
                                            __bf16* __restrict__ W1T,
                                            __bf16* __restrict__ W2T,
                                            __bf16* __restrict__ W3T,
                                            __bf16* __restrict__ WlT,
                                            __bf16* __restrict__ WrT,
                                            const int* __restrict__ deg,
                                            int* __restrict__ rowptr,
                                            int* __restrict__ cursor) {
    if (blockIdx.x == gridDim.x - 1) {      // dedicated scan block
        __shared__ int wtot[4], woff[4];
        int t = threadIdx.x, lane = t & 63, wv = t >> 6;
        const int chunk = (N_NODES + 255) / 256;   // 40
        int beg = t * chunk, end = beg + chunk;
        if (end > N_NODES) end = N_NODES;
        if (beg > N_NODES) beg = N_NODES;
        int s = 0;
        for (int j = beg; j < end; ++j) s += deg[j] + 1;   // +1 self-loop
        int v = s;
#pragma unroll
        for (int off = 1; off < 64; off <<= 1) {
            int o = __shfl_up(v, off);
            if (lane >= off) v += o;
        }
        if (lane == 63) wtot[wv] = v;
        __syncthreads();
        if (t == 0) {
            int r = 0;
#pragma unroll
            for (int w2 = 0; w2 < 4; ++w2) { woff[w2] = r; r += wtot[w2]; }
            rowptr[N_NODES] = r;
        }
        __syncthreads();
        int off = woff[wv] + v - s;
        for (int j = beg; j < end; ++j) {
            rowptr[j] = off; cursor[j] = off;
            off += deg[j] + 1;
        }
        return;
    }
    int i = blockIdx.x * 256 + threadIdx.x;
    if (i < S0V) {
        int base = i * 8;
        int row = base >> 9;
        bfrag8 r = {};
        if (row < N_NODES) {
            float4 f0 = ((const float4*)x)[i * 2];
            float4 f1 = ((const float4*)x)[i * 2 + 1];
            r[0] = (__bf16)f0.x; r[1] = (__bf16)f0.y; r[2] = (__bf16)f0.z; r[3] = (__bf16)f0.w;
            r[4] = (__bf16)f1.x; r[5] = (__bf16)f1.y; r[6] = (__bf16)f1.z; r[7] = (__bf16)f1.w;
        }
        *(bfrag8*)(xb + base) = r;
    } else if ((i -= S0V) < S1E) {          // W1: K=512, N=512
        int n = i & 511, kb = (i >> 9) * 8;
        bfrag8 r;
#pragma unroll
        for (int t = 0; t < 8; ++t) r[t] = (__bf16)W1[(kb + t) * 512 + n];
        *(bfrag8*)(W1T + n * 512 + kb) = r;
    } else if ((i -= S1E) < S2E) {          // W2
        int n = i & 511, kb = (i >> 9) * 8;
        bfrag8 r;
#pragma unroll
        for (int t = 0; t < 8; ++t) r[t] = (__bf16)W2[(kb + t) * 512 + n];
        *(bfrag8*)(W2T + n * 512 + kb) = r;
    } else if ((i -= S2E) < S3E) {          // W3: K=512, N=128
        int n = i & 127, kb = (i >> 7) * 8;
        bfrag8 r;
#pragma unroll
        for (int t = 0; t < 8; ++t) r[t] = (__bf16)W3[(kb + t) * 128 + n];
        *(bfrag8*)(W3T + n * 512 + kb) = r;
    } else if ((i -= S3E) < S4E) {          // Wl: K=128, N=256
        int n = i & 255, kb = (i >> 8) * 8;
        bfrag8 r;
#pragma unroll
        for (int t = 0; t < 8; ++t) r[t] = (__bf16)Wl[(kb + t) * 256 + n];
        *(bfrag8*)(WlT + n * 128 + kb) = r;
    } else if ((i -= S4E) < S5E) {          // Wr: K=512, N=256
        int n = i & 255, kb = (i >> 8) * 8;
        bfrag8 r;
#pragma unroll
        for (int t = 0; t < 8; ++t) r[t] = (__bf16)Wr[(kb + t) * 256 + n];
        *(bfrag8*)(WrT + n * 512 + kb) = r;
    }
}

// ---------------- MFMA GEMM K-loop, BK=64, tile 128(M) x 16*NT(N) (R5-proven) ----

template <int NT>
__device__ __forceinline__ void gemm_loop(const __bf16* __restrict__ A,
                                          const __bf16* __restrict__ BT, int K,
                                          int m0, int n0, int wave, int lane,
                                          __bf16* As, __bf16* Bs,
                                          floatx4 (&acc)[2][NT]) {
    int r = wave * 8 + (lane >> 3);          // 0..31 staging row
    int kof = (lane & 7) * 8;
    const __bf16* gA = A + (size_t)(m0 + r) * K + kof;
    const __bf16* gB = BT + (size_t)(n0 + r) * K + kof;
    __bf16* lA = As + r * 64 + kof;
    __bf16* lB = Bs + r * 64 + kof;
    const __bf16* fA = As + (wave * 32 + (lane & 15)) * 64 + (lane >> 4) * 8;
    const __bf16* fB = Bs + (lane & 15) * 64 + (lane >> 4) * 8;

    for (int k0 = 0; k0 < K; k0 += 64) {
#pragma unroll
        for (int u = 0; u < 4; ++u)
            __builtin_amdgcn_global_load_lds(
                (const __attribute__((address_space(1))) void*)(gA + (size_t)u * 32 * K),
                (__attribute__((address_space(3))) void*)(lA + u * 32 * 64), 16, 0, 0);
#pragma unroll
        for (int u = 0; u < NT / 2; ++u)
            __builtin_amdgcn_global_load_lds(
                (const __attribute__((address_space(1))) void*)(gB + (size_t)u * 32 * K),
                (__attribute__((address_space(3))) void*)(lB + u * 32 * 64), 16, 0, 0);
        gA += 64; gB += 64;
        __syncthreads();

#pragma unroll
        for (int ks = 0; ks < 2; ++ks) {
            bfrag8 a0 = *(const bfrag8*)(fA + ks * 32);
            bfrag8 a1 = *(const bfrag8*)(fA + 16 * 64 + ks * 32);
#pragma unroll
            for (int nt = 0; nt < NT; ++nt) {
                bfrag8 b = *(const bfrag8*)(fB + nt * 16 * 64 + ks * 32);
                acc[0][nt] = __builtin_amdgcn_mfma_f32_16x16x32_bf16(a0, b, acc[0][nt], 0, 0, 0);
                acc[1][nt] = __builtin_amdgcn_mfma_f32_16x16x32_bf16(a1, b, acc[1][nt], 0, 0, 0);
            }
        }
        __syncthreads();
    }
}

// one 128x128 tile of H = A@B^T, fp8 out + fused logit sums (full head per tile)
__device__ __forceinline__ void gemm_h_tile(const __bf16* __restrict__ A,
                                            const __bf16* __restrict__ BT,
                                            unsigned char* __restrict__ C8,
                                            int N, int K, int H,
                                            const float* __restrict__ as_,
                                            const float* __restrict__ ad_,
                                            float* __restrict__ esp,
                                            float* __restrict__ edp,
                                            int t, __bf16* As, __bf16* Bs,
                                            int wave, int lane) {
    int m0 = (t % 80) * 128, n0 = (t / 80) * 128;
    floatx4 acc[2][8] = {};
    gemm_loop<8>(A, BT, K, m0, n0, wave, lane, As, Bs, acc);

    int crow = m0 + wave * 32 + (lane >> 4) * 4;
    int ccol = n0 + (lane & 15);
#pragma unroll
    for (int mt = 0; mt < 2; ++mt)
#pragma unroll
        for (int nt = 0; nt < 8; ++nt)
#pragma unroll
            for (int r = 0; r < 4; ++r) {
                float v = acc[mt][nt][r];
                size_t o = (size_t)(crow + mt * 16 + r) * N + ccol + nt * 16;
                int p = __builtin_amdgcn_cvt_pk_fp8_f32(v, v, 0, false);
                C8[o] = (unsigned char)(p & 0xff);
            }

    int head = n0 >> 7;
    float a_sv[8], a_dv[8];
#pragma unroll
    for (int nt = 0; nt < 8; ++nt) {
        int cin = nt * 16 + (lane & 15);
        a_sv[nt] = as_[head * 128 + cin];
        a_dv[nt] = ad_[head * 128 + cin];
    }
#pragma unroll
    for (int mt = 0; mt < 2; ++mt)
#pragma unroll
        for (int r = 0; r < 4; ++r) {
            float ps = 0.f, pd = 0.f;
#pragma unroll
            for (int nt = 0; nt < 8; ++nt) {
                float v = acc[mt][nt][r];
                ps += v * a_sv[nt];
                pd += v * a_dv[nt];
            }
#pragma unroll
            for (int off = 8; off; off >>= 1) {
                ps += __shfl_xor(ps, off);
                pd += __shfl_xor(pd, off);
            }
            if ((lane & 15) == 0) {
                int row = crow + mt * 16 + r;
                esp[row * H + head] = ps;
                edp[row * H + head] = pd;
            }
        }
}

// standalone gemm_h (layer 2): grid (80, H)
__global__ __launch_bounds__(256) void gemm_h(const __bf16* __restrict__ A,
                                              const __bf16* __restrict__ BT,
                                              unsigned char* __restrict__ C8,
                                              int N, int K, int H,
                                              const float* __restrict__ as_,
                                              const float* __restrict__ ad_,
                                              float* __restrict__ esp,
                                              float* __restrict__ edp) {
    __shared__ __align__(16) __bf16 As[128 * 64];
    __shared__ __align__(16) __bf16 Bs[128 * 64];
    int tid = threadIdx.x, wave = tid >> 6, lane = tid & 63;
    int t = blockIdx.x + 80 * blockIdx.y;
    gemm_h_tile(A, BT, C8, N, K, H, as_, ad_, esp, edp, t, As, Bs, wave, lane);
}

// merged: gemm_h layer 1 (blocks 0..319) + CSR scatter (blocks >= 320).
__global__ __launch_bounds__(256) void gemm1s(const __bf16* __restrict__ A,
                                              const __bf16* __restrict__ BT,
                                              unsigned char* __restrict__ C8,
                                              const float* __restrict__ as_,
                                              const float* __restrict__ ad_,
                                              float* __restrict__ esp,
                                              float* __restrict__ edp,
                                              const int* __restrict__ esrc,
                                              const int* __restrict__ edst, int E,
                                              int* __restrict__ cursor,
                                              int* __restrict__ csr) {
    __shared__ __align__(16) __bf16 As[128 * 64];
    __shared__ __align__(16) __bf16 Bs[128 * 64];
    int bid = blockIdx.x;
    if (bid >= 320) {
        int i = (bid - 320) * 256 + threadIdx.x;
        if (i < E) {
            int pos = atomicAdd(&cursor[edst[i]], 1);
            csr[pos] = esrc[i];
        } else if (i < E + N_NODES) {
            int v = i - E;
            int pos = atomicAdd(&cursor[v], 1);
            csr[pos] = v;                              // self-loop
        }
        return;
    }
    int tid = threadIdx.x, wave = tid >> 6, lane = tid & 63;
    gemm_h_tile(A, BT, C8, 512, 512, 4, as_, ad_, esp, edp, bid, As, Bs, wave, lane);
}

// merged: gemm_h layer 3 (blocks 0..79, H=1 N=128) + residual out = xb@WrT + br
__global__ __launch_bounds__(256) void gemm3r(const __bf16* __restrict__ hb,
                                              const __bf16* __restrict__ W3T,
                                              unsigned char* __restrict__ C8,
                                              const float* __restrict__ a3s,
                                              const float* __restrict__ a3d,
                                              float* __restrict__ esp,
                                              float* __restrict__ edp,
                                              const __bf16* __restrict__ xb,
                                              const __bf16* __restrict__ WrT,
                                              const float* __restrict__ br,
                                              float* __restrict__ out) {
    __shared__ __align__(16) __bf16 As[128 * 64];
    __shared__ __align__(16) __bf16 Bs[128 * 64];
    int tid = threadIdx.x, wave = tid >> 6, lane = tid & 63;
    int bid = blockIdx.x;
    if (bid < 80) {
        gemm_h_tile(hb, W3T, C8, 128, 512, 1, a3s, a3d, esp, edp, bid, As, Bs, wave, lane);
        return;
    }
    int t = bid - 80;
    int m0 = (t % 80) * 128, n0 = (t / 80) * 64;
    floatx4 acc[2][4] = {};
    gemm_loop<4>(xb, WrT, 512, m0, n0, wave, lane, As, Bs, acc);

    int crow = m0 + wave * 32 + (lane >> 4) * 4;
    int ccol = n0 + (lane & 15);
#pragma unroll
    for (int mt = 0; mt < 2; ++mt)
#pragma unroll
        for (int nt = 0; nt < 4; ++nt)
#pragma unroll
            for (int r = 0; r < 4; ++r) {
                int row = crow + mt * 16 + r;
                int col = ccol + nt * 16;
                if (row < N_NODES)
                    out[(size_t)row * 256 + col] = acc[mt][nt][r] + br[col];
            }
}

// final accumulate: out += hb3@WlT^T + bl  (K=128 only)
__global__ __launch_bounds__(256) void gemm_acc(const __bf16* __restrict__ hb3,
                                                const __bf16* __restrict__ WlT,
                                                float* __restrict__ out,
                                                const float* __restrict__ bl) {
    __shared__ __align__(16) __bf16 As[128 * 64];
    __shared__ __align__(16) __bf16 Bs[64 * 64];
    int tid = threadIdx.x, wave = tid >> 6, lane = tid & 63;
    int m0 = blockIdx.x * 128, n0 = blockIdx.y * 64;
    floatx4 acc[2][4] = {};
    gemm_loop<4>(hb3, WlT, 128, m0, n0, wave, lane, As, Bs, acc);

    int crow = m0 + wave * 32 + (lane >> 4) * 4;
    int ccol = n0 + (lane & 15);
#pragma unroll
    for (int mt = 0; mt < 2; ++mt)
#pragma unroll
        for (int nt = 0; nt < 4; ++nt)
#pragma unroll
            for (int r = 0; r < 4; ++r) {
                int row = crow + mt * 16 + r;
                int col = ccol + nt * 16;
                if (row < N_NODES) {
                    size_t o = (size_t)row * 256 + col;
                    out[o] = out[o] + acc[mt][nt][r] + bl[col];
                }
            }
}

// ---------------- fused softmax + weighted gather, fp8 H; pass2 8-deep ----------------

template <int H>
__global__ __launch_bounds__(256) void gather_agg(const unsigned char* __restrict__ H8,
                                                  const float* __restrict__ esp,
                                                  const float* __restrict__ edp,
                                                  const int* __restrict__ rowptr,
                                                  const int* __restrict__ csr,
                                                  const float* __restrict__ bias,
                                                  __bf16* __restrict__ outb) {
    constexpr int F = H * 128;
    constexpr int CH = F / 64;          // 8 or 2
    __shared__ int   sIdx[4][64];
    __shared__ float sWgt[4][64 * H];
    int wave = threadIdx.x >> 6, lane = threadIdx.x & 63;
    int node = blockIdx.x * 4 + wave;
    if (node >= M_PAD) return;
    __bf16* op = outb + (size_t)node * F + lane * CH;
    if (node >= N_NODES) {
        if (H == 4) { bfrag8 z = {}; *(bfrag8*)op = z; }
        else        { bfrag2 z = {}; *(bfrag2*)op = z; }
        return;
    }
    int hsel = (H == 4) ? (lane >> 4) : 0;
    const unsigned char* hp = H8 + lane * CH;
    int beg = rowptr[node], end = rowptr[node + 1];
    float acc[CH] = {};
    float wsum = 0.f;

    float edv0 = 0.f, edv1 = 0.f, edv2 = 0.f, edv3 = 0.f;
    if (H == 4) {
        float4 e4 = *(const float4*)(edp + node * 4);
        edv0 = e4.x; edv1 = e4.y; edv2 = e4.z; edv3 = e4.w;
    } else {
        edv0 = edp[node];
    }

    for (int t0 = beg; t0 < end; t0 += 64) {
        int n_t = end - t0; if (n_t > 64) n_t = 64;
        // pass 1: one lane per edge, all H logits once
        if (lane < n_t) {
            int s = csr[t0 + lane];
            sIdx[wave][lane] = s;
            if (H == 4) {
                float4 es = *(const float4*)(esp + s * 4);
                float tt0 = es.x + edv0; tt0 = tt0 > 0.f ? tt0 : 0.2f * tt0;
                float tt1 = es.y + edv1; tt1 = tt1 > 0.f ? tt1 : 0.2f * tt1;
                float tt2 = es.z + edv2; tt2 = tt2 > 0.f ? tt2 : 0.2f * tt2;
                float tt3 = es.w + edv3; tt3 = tt3 > 0.f ? tt3 : 0.2f * tt3;
                floatx4 w4 = { __expf(tt0), __expf(tt1), __expf(tt2), __expf(tt3) };
                *(floatx4*)&sWgt[wave][lane * 4] = w4;
            } else {
                float tt = esp[s] + edv0; tt = tt > 0.f ? tt : 0.2f * tt;
                sWgt[wave][lane] = __expf(tt);
            }
        }
        asm volatile("s_waitcnt lgkmcnt(0)" ::: "memory");

        // pass 2: weighted gather, 8-deep pipelined (weights are LDS-resident,
        // so the H8 row loads have no dependent-load chain and overlap freely)
        int e = 0;
        for (; e + 7 < n_t; e += 8) {
            int s8[8]; float w8[8];
#pragma unroll
            for (int u = 0; u < 8; ++u) {
                s8[u] = sIdx[wave][e + u];
                w8[u] = sWgt[wave][(e + u) * H + hsel];
            }
            if (H == 4) {
                uint2 p8[8];
#pragma unroll
                for (int u = 0; u < 8; ++u) p8[u] = *(const uint2*)(hp + (size_t)s8[u] * F);
#pragma unroll
                for (int u = 0; u < 8; ++u) {
                    float wgt = w8[u];
                    wsum += wgt;
                    floatx2 f0 = __builtin_amdgcn_cvt_pk_f32_fp8(p8[u].x, false);
                    floatx2 f1 = __builtin_amdgcn_cvt_pk_f32_fp8(p8[u].x, true);
                    floatx2 f2 = __builtin_amdgcn_cvt_pk_f32_fp8(p8[u].y, false);
                    floatx2 f3 = __builtin_amdgcn_cvt_pk_f32_fp8(p8[u].y, true);
                    acc[0] += wgt * f0[0]; acc[1] += wgt * f0[1];
                    acc[2] += wgt * f1[0]; acc[3] += wgt * f1[1];
                    acc[4] += wgt * f2[0]; acc[5] += wgt * f2[1];
                    acc[6] += wgt * f3[0]; acc[7] += wgt * f3[1];
                }
            } else {
                unsigned short p8[8];
#pragma unroll
                for (int u = 0; u < 8; ++u) p8[u] = *(const unsigned short*)(hp + (size_t)s8[u] * F);
#pragma unroll
                for (int u = 0; u < 8; ++u) {
                    float wgt = w8[u];
                    wsum += wgt;
                    floatx2 f0 = __builtin_amdgcn_cvt_pk_f32_fp8((int)p8[u], false);
                    acc[0] += wgt * f0[0]; acc[1] += wgt * f0[1];
                }
            }
        }
        for (; e < n_t; ++e) {
            int s0 = sIdx[wave][e];
            float wgt = sWgt[wave][e * H + hsel];
            wsum += wgt;
            if (H == 4) {
                uint2 p = *(const uint2*)(hp + (size_t)s0 * F);
                floatx2 f0 = __builtin_amdgcn_cvt_pk_f32_fp8(p.x, false);
                floatx2 f1 = __builtin_amdgcn_cvt_pk_f32_fp8(p.x, true);
                floatx2 f2 = __builtin_amdgcn_cvt_pk_f32_fp8(p.y, false);
                floatx2 f3 = __builtin_amdgcn_cvt_pk_f32_fp8(p.y, true);
                acc[0] += wgt * f0[0]; acc[1] += wgt * f0[1];
                acc[2] += wgt * f1[0]; acc[3] += wgt * f1[1];
                acc[4] += wgt * f2[0]; acc[5] += wgt * f2[1];
                acc[6] += wgt * f3[0]; acc[7] += wgt * f3[1];
            } else {
                unsigned short p = *(const unsigned short*)(hp + (size_t)s0 * F);
                floatx2 f0 = __builtin_amdgcn_cvt_pk_f32_fp8((int)p, false);
                acc[0] += wgt * f0[0]; acc[1] += wgt * f0[1];
            }
        }
    }

    float inv = 1.f / (wsum + 1e-16f);
    if (H == 4) {
        bfrag8 r;
#pragma unroll
        for (int k = 0; k < 8; ++k) {
            float o = acc[k] * inv + bias[lane * 8 + k];
            o = o > 0.f ? o : __expf(o) - 1.f;     // ELU
            r[k] = (__bf16)o;
        }
        *(bfrag8*)op = r;
    } else {
        bfrag2 r;
#pragma unroll
        for (int k = 0; k < 2; ++k) {
            float o = acc[k] * inv + bias[lane * 2 + k];
            o = o > 0.f ? o : __expf(o) - 1.f;
            r[k] = (__bf16)o;
        }
        *(bfrag2*)op = r;
    }
}

// ---------------- launch ----------------

extern "C" void kernel_launch(void* const* d_in, const int* in_sizes, int n_in,
                              void* d_out, int out_size, void* d_ws, size_t ws_size,
                              hipStream_t stream) {
    const float* x   = (const float*)d_in[0];
    const float* W1  = (const float*)d_in[1];
    const float* a1s = (const float*)d_in[2];
    const float* a1d = (const float*)d_in[3];
    const float* b1  = (const float*)d_in[4];
    const float* W2  = (const float*)d_in[5];
    const float* a2s = (const float*)d_in[6];
    const float* a2d = (const float*)d_in[7];
    const float* b2  = (const float*)d_in[8];
    const float* W3  = (const float*)d_in[9];
    const float* a3s = (const float*)d_in[10];
    const float* a3d = (const float*)d_in[11];
    const float* b3  = (const float*)d_in[12];
    const float* Wl  = (const float*)d_in[13];
    const float* bl  = (const float*)d_in[14];
    const float* Wr  = (const float*)d_in[15];
    const float* br  = (const float*)d_in[16];
    const int*   ei  = (const int*)d_in[17];
    const int E = in_sizes[17] / 2;
    const int* esrc = ei;
    const int* edst = ei + E;
    const int slots = E + N_NODES;
    float* out = (float*)d_out;

    char* w = (char*)d_ws;
    auto alloc = [&](size_t b) { char* p = w; w += (b + 255) & ~(size_t)255; return p; };
    __bf16* xb  = (__bf16*)alloc((size_t)M_PAD * 512 * 2);
    __bf16* hb  = (__bf16*)alloc((size_t)M_PAD * 512 * 2);
    __bf16* hb3 = (__bf16*)alloc((size_t)M_PAD * 128 * 2);
    unsigned char* Hi8 = (unsigned char*)alloc((size_t)M_PAD * 512);
    __bf16* W1T = (__bf16*)alloc(512 * 512 * 2);
    __bf16* W2T = (__bf16*)alloc(512 * 512 * 2);
    __bf16* W3T = (__bf16*)alloc(128 * 512 * 2);
    __bf16* WlT = (__bf16*)alloc(256 * 128 * 2);
    __bf16* WrT = (__bf16*)alloc(256 * 512 * 2);
    float* esp    = (float*)alloc((size_t)M_PAD * HEADS * 4);
    float* edp    = (float*)alloc((size_t)M_PAD * HEADS * 4);
    int*   deg    = (int*)alloc(N_NODES * 4);
    int*   rowptr = (int*)alloc((N_NODES + 1) * 4);
    int*   cursor = (int*)alloc(N_NODES * 4);
    int*   csr    = (int*)alloc((size_t)slots * 4);

    (void)hipMemsetAsync(deg, 0, N_NODES * sizeof(int), stream);

    // deg count first, so prep's scan block sees completed deg[]
    deg_count<<<(E + 255) / 256, 256, 0, stream>>>(edst, E, deg);

    const int sp_total = S0V + S1E + S2E + S3E + S4E + S5E;
    prep<<<sp_total / 256 + 1, 256, 0, stream>>>(x, W1, W2, W3, Wl, Wr,
                                                 xb, W1T, W2T, W3T, WlT, WrT,
                                                 deg, rowptr, cursor);

    const int scat_blocks = (E + N_NODES + 255) / 256;
    // layer 1 GEMM + CSR scatter (one dispatch)
    gemm1s<<<320 + scat_blocks, 256, 0, stream>>>(xb, W1T, Hi8, a1s, a1d, esp, edp,
                                                  esrc, edst, E, cursor, csr);
    gather_agg<4><<<M_PAD / 4, 256, 0, stream>>>(Hi8, esp, edp, rowptr, csr, b1, hb);
    // layer 2
    gemm_h<<<dim3(80, 4), 256, 0, stream>>>(hb, W2T, Hi8, 512, 512, 4,
                                            a2s, a2d, esp, edp);
    gather_agg<4><<<M_PAD / 4, 256, 0, stream>>>(Hi8, esp, edp, rowptr, csr, b2, hb);
    // layer 3 (H=1) + residual out = xb@WrT + br (one dispatch)
    gemm3r<<<400, 256, 0, stream>>>(hb, W3T, Hi8, a3s, a3d, esp, edp,
                                    xb, WrT, br, out);
    gather_agg<1><<<M_PAD / 4, 256, 0, stream>>>(Hi8, esp, edp, rowptr, csr, b3, hb3);
    // final: out += hb3@WlT + bl (K=128)
    gemm_acc<<<dim3(80, 4), 256, 0, stream>>>(hb3, WlT, out, bl);
}

// Round 9
// 235.995 us; speedup vs baseline: 1.1590x; 1.0521x over previous
//
#include <hip/hip_runtime.h>
#include <hip/hip_bf16.h>
#include <cstdint>
#include <cstddef>

#define N_NODES 10000
#define M_PAD   10240   // 80 panels of 128; 80 % 8 == 0 -> panel%8 = XCD under round-robin
#define HEADS   4

typedef __bf16 bfrag8 __attribute__((ext_vector_type(8)));
typedef __bf16 bfrag2 __attribute__((ext_vector_type(2)));
typedef float  floatx4 __attribute__((ext_vector_type(4)));
typedef float  floatx2 __attribute__((ext_vector_type(2)));

#define S0V (M_PAD * 512 / 8)   // xb
#define S1E (512 * 512 / 8)     // W1T
#define S2E (512 * 512 / 8)     // W2T
#define S3E (512 * 128 / 8)     // W3T
#define S4E (128 * 256 / 8)     // WlT
#define S5E (512 * 256 / 8)     // WrT

// ---------------- prep: x->bf16 pad, 5 weight transposes, degree count.
// R5-proven form: deg atomics hidden inside the wide grid; NO tail work
// (R4/R6/R8 lessons: in-kernel completion protocols and serial deg hoists
// both lose to this layout). ----

__global__ __launch_bounds__(256) void prep(const float* __restrict__ x,
                                            const float* __restrict__ W1,
                                            const float* __restrict__ W2,
                                            const float* __restrict__ W3,
                                            const float* __restrict__ Wl,
                                            const float* __restrict__ Wr,
                                            const int* __restrict__ edst, int E,
                                            __bf16* __restrict__ xb,
                                            __bf16* __restrict__ W1T,
                                            __bf16* __restrict__ W2T,
                                            __bf16* __restrict__ W3T,
                                            __bf16* __restrict__ WlT,
                                            __bf16* __restrict__ WrT,
                                            int* __restrict__ deg) {
    int i = blockIdx.x * 256 + threadIdx.x;
    if (i < S0V) {
        int base = i * 8;
        int row = base >> 9;
        bfrag8 r = {};
        if (row < N_NODES) {
            float4 f0 = ((const float4*)x)[i * 2];
            float4 f1 = ((const float4*)x)[i * 2 + 1];
            r[0] = (__bf16)f0.x; r[1] = (__bf16)f0.y; r[2] = (__bf16)f0.z; r[3] = (__bf16)f0.w;
            r[4] = (__bf16)f1.x; r[5] = (__bf16)f1.y; r[6] = (__bf16)f1.z; r[7] = (__bf16)f1.w;
        }
        *(bfrag8*)(xb + base) = r;
    } else if ((i -= S0V) < S1E) {          // W1: K=512, N=512
        int n = i & 511, kb = (i >> 9) * 8;
        bfrag8 r;
#pragma unroll
        for (int t = 0; t < 8; ++t) r[t] = (__bf16)W1[(kb + t) * 512 + n];
        *(bfrag8*)(W1T + n * 512 + kb) = r;
    } else if ((i -= S1E) < S2E) {          // W2
        int n = i & 511, kb = (i >> 9) * 8;
        bfrag8 r;
#pragma unroll
        for (int t = 0; t < 8; ++t) r[t] = (__bf16)W2[(kb + t) * 512 + n];
        *(bfrag8*)(W2T + n * 512 + kb) = r;
    } else if ((i -= S2E) < S3E) {          // W3: K=512, N=128
        int n = i & 127, kb = (i >> 7) * 8;
        bfrag8 r;
#pragma unroll
        for (int t = 0; t < 8; ++t) r[t] = (__bf16)W3[(kb + t) * 128 + n];
        *(bfrag8*)(W3T + n * 512 + kb) = r;
    } else if ((i -= S3E) < S4E) {          // Wl: K=128, N=256
        int n = i & 255, kb = (i >> 8) * 8;
        bfrag8 r;
#pragma unroll
        for (int t = 0; t < 8; ++t) r[t] = (__bf16)Wl[(kb + t) * 256 + n];
        *(bfrag8*)(WlT + n * 128 + kb) = r;
    } else if ((i -= S4E) < S5E) {          // Wr: K=512, N=256
        int n = i & 255, kb = (i >> 8) * 8;
        bfrag8 r;
#pragma unroll
        for (int t = 0; t < 8; ++t) r[t] = (__bf16)Wr[(kb + t) * 256 + n];
        *(bfrag8*)(WrT + n * 512 + kb) = r;
    } else if ((i -= S5E) < E) {
        atomicAdd(&deg[edst[i]], 1);
    }
}

// ---------------- CSR scan: 1024 threads, chunk=10 rows/thread (R2-proven) ----

__global__ __launch_bounds__(1024) void scan_kernel(const int* __restrict__ deg,
                                                    int* __restrict__ rowptr,
                                                    int* __restrict__ cursor, int n) {
    __shared__ int wtot[16], woff[16];
    int t = threadIdx.x, lane = t & 63, wv = t >> 6;
    int chunk = (n + 1023) / 1024;
    int beg = t * chunk, end = beg + chunk; if (end > n) end = n; if (beg > n) beg = n;
    int s = 0;
    for (int i = beg; i < end; ++i) s += deg[i] + 1;   // +1 self-loop
    int v = s;
#pragma unroll
    for (int off = 1; off < 64; off <<= 1) {
        int o = __shfl_up(v, off);
        if (lane >= off) v += o;
    }
    if (lane == 63) wtot[wv] = v;
    __syncthreads();
    if (t == 0) {
        int r = 0;
#pragma unroll
        for (int i = 0; i < 16; ++i) { woff[i] = r; r += wtot[i]; }
        rowptr[n] = r;
    }
    __syncthreads();
    int off = woff[wv] + v - s;     // exclusive prefix
    for (int i = beg; i < end; ++i) {
        rowptr[i] = off; cursor[i] = off;
        off += deg[i] + 1;
    }
}

// ---------------- MFMA GEMM K-loop, BK=64, tile 128(M) x 16*NT(N) (R5-proven) ----

template <int NT>
__device__ __forceinline__ void gemm_loop(const __bf16* __restrict__ A,
                                          const __bf16* __restrict__ BT, int K,
                                          int m0, int n0, int wave, int lane,
                                          __bf16* As, __bf16* Bs,
                                          floatx4 (&acc)[2][NT]) {
    int r = wave * 8 + (lane >> 3);          // 0..31 staging row
    int kof = (lane & 7) * 8;
    const __bf16* gA = A + (size_t)(m0 + r) * K + kof;
    const __bf16* gB = BT + (size_t)(n0 + r) * K + kof;
    __bf16* lA = As + r * 64 + kof;
    __bf16* lB = Bs + r * 64 + kof;
    const __bf16* fA = As + (wave * 32 + (lane & 15)) * 64 + (lane >> 4) * 8;
    const __bf16* fB = Bs + (lane & 15) * 64 + (lane >> 4) * 8;

    for (int k0 = 0; k0 < K; k0 += 64) {
#pragma unroll
        for (int u = 0; u < 4; ++u)
            __builtin_amdgcn_global_load_lds(
                (const __attribute__((address_space(1))) void*)(gA + (size_t)u * 32 * K),
                (__attribute__((address_space(3))) void*)(lA + u * 32 * 64), 16, 0, 0);
#pragma unroll
        for (int u = 0; u < NT / 2; ++u)
            __builtin_amdgcn_global_load_lds(
                (const __attribute__((address_space(1))) void*)(gB + (size_t)u * 32 * K),
                (__attribute__((address_space(3))) void*)(lB + u * 32 * 64), 16, 0, 0);
        gA += 64; gB += 64;
        __syncthreads();

#pragma unroll
        for (int ks = 0; ks < 2; ++ks) {
            bfrag8 a0 = *(const bfrag8*)(fA + ks * 32);
            bfrag8 a1 = *(const bfrag8*)(fA + 16 * 64 + ks * 32);
#pragma unroll
            for (int nt = 0; nt < NT; ++nt) {
                bfrag8 b = *(const bfrag8*)(fB + nt * 16 * 64 + ks * 32);
                acc[0][nt] = __builtin_amdgcn_mfma_f32_16x16x32_bf16(a0, b, acc[0][nt], 0, 0, 0);
                acc[1][nt] = __builtin_amdgcn_mfma_f32_16x16x32_bf16(a1, b, acc[1][nt], 0, 0, 0);
            }
        }
        __syncthreads();
    }
}

// one 128x128 tile of H = A@B^T, fp8 out + fused logit sums (full head per tile)
__device__ __forceinline__ void gemm_h_tile(const __bf16* __restrict__ A,
                                            const __bf16* __restrict__ BT,
                                            unsigned char* __restrict__ C8,
                                            int N, int K, int H,
                                            const float* __restrict__ as_,
                                            const float* __restrict__ ad_,
                                            float* __restrict__ esp,
                                            float* __restrict__ edp,
                                            int t, __bf16* As, __bf16* Bs,
                                            int wave, int lane) {
    int m0 = (t % 80) * 128, n0 = (t / 80) * 128;
    floatx4 acc[2][8] = {};
    gemm_loop<8>(A, BT, K, m0, n0, wave, lane, As, Bs, acc);

    int crow = m0 + wave * 32 + (lane >> 4) * 4;
    int ccol = n0 + (lane & 15);
#pragma unroll
    for (int mt = 0; mt < 2; ++mt)
#pragma unroll
        for (int nt = 0; nt < 8; ++nt)
#pragma unroll
            for (int r = 0; r < 4; ++r) {
                float v = acc[mt][nt][r];
                size_t o = (size_t)(crow + mt * 16 + r) * N + ccol + nt * 16;
                int p = __builtin_amdgcn_cvt_pk_fp8_f32(v, v, 0, false);
                C8[o] = (unsigned char)(p & 0xff);
            }

    int head = n0 >> 7;
    float a_sv[8], a_dv[8];
#pragma unroll
    for (int nt = 0; nt < 8; ++nt) {
        int cin = nt * 16 + (lane & 15);
        a_sv[nt] = as_[head * 128 + cin];
        a_dv[nt] = ad_[head * 128 + cin];
    }
#pragma unroll
    for (int mt = 0; mt < 2; ++mt)
#pragma unroll
        for (int r = 0; r < 4; ++r) {
            float ps = 0.f, pd = 0.f;
#pragma unroll
            for (int nt = 0; nt < 8; ++nt) {
                float v = acc[mt][nt][r];
                ps += v * a_sv[nt];
                pd += v * a_dv[nt];
            }
#pragma unroll
            for (int off = 8; off; off >>= 1) {
                ps += __shfl_xor(ps, off);
                pd += __shfl_xor(pd, off);
            }
            if ((lane & 15) == 0) {
                int row = crow + mt * 16 + r;
                esp[row * H + head] = ps;
                edp[row * H + head] = pd;
            }
        }
}

// standalone gemm_h (layer 2): grid (80, H)
__global__ __launch_bounds__(256) void gemm_h(const __bf16* __restrict__ A,
                                              const __bf16* __restrict__ BT,
                                              unsigned char* __restrict__ C8,
                                              int N, int K, int H,
                                              const float* __restrict__ as_,
                                              const float* __restrict__ ad_,
                                              float* __restrict__ esp,
                                              float* __restrict__ edp) {
    __shared__ __align__(16) __bf16 As[128 * 64];
    __shared__ __align__(16) __bf16 Bs[128 * 64];
    int tid = threadIdx.x, wave = tid >> 6, lane = tid & 63;
    int t = blockIdx.x + 80 * blockIdx.y;
    gemm_h_tile(A, BT, C8, N, K, H, as_, ad_, esp, edp, t, As, Bs, wave, lane);
}

// merged: gemm_h layer 1 (blocks 0..319) + CSR scatter (blocks >= 320).
__global__ __launch_bounds__(256) void gemm1s(const __bf16* __restrict__ A,
                                              const __bf16* __restrict__ BT,
                                              unsigned char* __restrict__ C8,
                                              const float* __restrict__ as_,
                                              const float* __restrict__ ad_,
                                              float* __restrict__ esp,
                                              float* __restrict__ edp,
                                              const int* __restrict__ esrc,
                                              const int* __restrict__ edst, int E,
                                              int* __restrict__ cursor,
                                              int* __restrict__ csr) {
    __shared__ __align__(16) __bf16 As[128 * 64];
    __shared__ __align__(16) __bf16 Bs[128 * 64];
    int bid = blockIdx.x;
    if (bid >= 320) {
        int i = (bid - 320) * 256 + threadIdx.x;
        if (i < E) {
            int pos = atomicAdd(&cursor[edst[i]], 1);
            csr[pos] = esrc[i];
        } else if (i < E + N_NODES) {
            int v = i - E;
            int pos = atomicAdd(&cursor[v], 1);
            csr[pos] = v;                              // self-loop
        }
        return;
    }
    int tid = threadIdx.x, wave = tid >> 6, lane = tid & 63;
    gemm_h_tile(A, BT, C8, 512, 512, 4, as_, ad_, esp, edp, bid, As, Bs, wave, lane);
}

// merged: gemm_h layer 3 (blocks 0..79, H=1 N=128) + residual out = xb@WrT + br
__global__ __launch_bounds__(256) void gemm3r(const __bf16* __restrict__ hb,
                                              const __bf16* __restrict__ W3T,
                                              unsigned char* __restrict__ C8,
                                              const float* __restrict__ a3s,
                                              const float* __restrict__ a3d,
                                              float* __restrict__ esp,
                                              float* __restrict__ edp,
                                              const __bf16* __restrict__ xb,
                                              const __bf16* __restrict__ WrT,
                                              const float* __restrict__ br,
                                              float* __restrict__ out) {
    __shared__ __align__(16) __bf16 As[128 * 64];
    __shared__ __align__(16) __bf16 Bs[128 * 64];
    int tid = threadIdx.x, wave = tid >> 6, lane = tid & 63;
    int bid = blockIdx.x;
    if (bid < 80) {
        gemm_h_tile(hb, W3T, C8, 128, 512, 1, a3s, a3d, esp, edp, bid, As, Bs, wave, lane);
        return;
    }
    int t = bid - 80;
    int m0 = (t % 80) * 128, n0 = (t / 80) * 64;
    floatx4 acc[2][4] = {};
    gemm_loop<4>(xb, WrT, 512, m0, n0, wave, lane, As, Bs, acc);

    int crow = m0 + wave * 32 + (lane >> 4) * 4;
    int ccol = n0 + (lane & 15);
#pragma unroll
    for (int mt = 0; mt < 2; ++mt)
#pragma unroll
        for (int nt = 0; nt < 4; ++nt)
#pragma unroll
            for (int r = 0; r < 4; ++r) {
                int row = crow + mt * 16 + r;
                int col = ccol + nt * 16;
                if (row < N_NODES)
                    out[(size_t)row * 256 + col] = acc[mt][nt][r] + br[col];
            }
}

// final accumulate: out += hb3@WlT^T + bl  (K=128 only)
__global__ __launch_bounds__(256) void gemm_acc(const __bf16* __restrict__ hb3,
                                                const __bf16* __restrict__ WlT,
                                                float* __restrict__ out,
                                                const float* __restrict__ bl) {
    __shared__ __align__(16) __bf16 As[128 * 64];
    __shared__ __align__(16) __bf16 Bs[64 * 64];
    int tid = threadIdx.x, wave = tid >> 6, lane = tid & 63;
    int m0 = blockIdx.x * 128, n0 = blockIdx.y * 64;
    floatx4 acc[2][4] = {};
    gemm_loop<4>(hb3, WlT, 128, m0, n0, wave, lane, As, Bs, acc);

    int crow = m0 + wave * 32 + (lane >> 4) * 4;
    int ccol = n0 + (lane & 15);
#pragma unroll
    for (int mt = 0; mt < 2; ++mt)
#pragma unroll
        for (int nt = 0; nt < 4; ++nt)
#pragma unroll
            for (int r = 0; r < 4; ++r) {
                int row = crow + mt * 16 + r;
                int col = ccol + nt * 16;
                if (row < N_NODES) {
                    size_t o = (size_t)row * 256 + col;
                    out[o] = out[o] + acc[mt][nt][r] + bl[col];
                }
            }
}

// ---------------- fused softmax + weighted gather, fp8 H (R2/R5-proven) ----------------

template <int H>
__global__ __launch_bounds__(256) void gather_agg(const unsigned char* __restrict__ H8,
                                                  const float* __restrict__ esp,
                                                  const float* __restrict__ edp,
                                                  const int* __restrict__ rowptr,
                                                  const int* __restrict__ csr,
                                                  const float* __restrict__ bias,
                                                  __bf16* __restrict__ outb) {
    constexpr int F = H * 128;
    constexpr int CH = F / 64;          // 8 or 2
    __shared__ int   sIdx[4][64];
    __shared__ float sWgt[4][64 * H];
    int wave = threadIdx.x >> 6, lane = threadIdx.x & 63;
    int node = blockIdx.x * 4 + wave;
    if (node >= M_PAD) return;
    __bf16* op = outb + (size_t)node * F + lane * CH;
    if (node >= N_NODES) {
        if (H == 4) { bfrag8 z = {}; *(bfrag8*)op = z; }
        else        { bfrag2 z = {}; *(bfrag2*)op = z; }
        return;
    }
    int hsel = (H == 4) ? (lane >> 4) : 0;
    const unsigned char* hp = H8 + lane * CH;
    int beg = rowptr[node], end = rowptr[node + 1];
    float acc[CH] = {};
    float wsum = 0.f;

    float edv0 = 0.f, edv1 = 0.f, edv2 = 0.f, edv3 = 0.f;
    if (H == 4) {
        float4 e4 = *(const float4*)(edp + node * 4);
        edv0 = e4.x; edv1 = e4.y; edv2 = e4.z; edv3 = e4.w;
    } else {
        edv0 = edp[node];
    }

    for (int t0 = beg; t0 < end; t0 += 64) {
        int n_t = end - t0; if (n_t > 64) n_t = 64;
        // pass 1: one lane per edge, all H logits once
        if (lane < n_t) {
            int s = csr[t0 + lane];
            sIdx[wave][lane] = s;
            if (H == 4) {
                float4 es = *(const float4*)(esp + s * 4);
                float tt0 = es.x + edv0; tt0 = tt0 > 0.f ? tt0 : 0.2f * tt0;
                float tt1 = es.y + edv1; tt1 = tt1 > 0.f ? tt1 : 0.2f * tt1;
                float tt2 = es.z + edv2; tt2 = tt2 > 0.f ? tt2 : 0.2f * tt2;
                float tt3 = es.w + edv3; tt3 = tt3 > 0.f ? tt3 : 0.2f * tt3;
                floatx4 w4 = { __expf(tt0), __expf(tt1), __expf(tt2), __expf(tt3) };
                *(floatx4*)&sWgt[wave][lane * 4] = w4;
            } else {
                float tt = esp[s] + edv0; tt = tt > 0.f ? tt : 0.2f * tt;
                sWgt[wave][lane] = __expf(tt);
            }
        }
        asm volatile("s_waitcnt lgkmcnt(0)" ::: "memory");

        // pass 2: weighted gather, 4-deep pipelined
        int e = 0;
        for (; e + 3 < n_t; e += 4) {
            int s4[4]; float w4[4];
#pragma unroll
            for (int u = 0; u < 4; ++u) {
                s4[u] = sIdx[wave][e + u];
                w4[u] = sWgt[wave][(e + u) * H + hsel];
            }
            if (H == 4) {
                uint2 p4[4];
#pragma unroll
                for (int u = 0; u < 4; ++u) p4[u] = *(const uint2*)(hp + (size_t)s4[u] * F);
#pragma unroll
                for (int u = 0; u < 4; ++u) {
                    float wgt = w4[u];
                    wsum += wgt;
                    floatx2 f0 = __builtin_amdgcn_cvt_pk_f32_fp8(p4[u].x, false);
                    floatx2 f1 = __builtin_amdgcn_cvt_pk_f32_fp8(p4[u].x, true);
                    floatx2 f2 = __builtin_amdgcn_cvt_pk_f32_fp8(p4[u].y, false);
                    floatx2 f3 = __builtin_amdgcn_cvt_pk_f32_fp8(p4[u].y, true);
                    acc[0] += wgt * f0[0]; acc[1] += wgt * f0[1];
                    acc[2] += wgt * f1[0]; acc[3] += wgt * f1[1];
                    acc[4] += wgt * f2[0]; acc[5] += wgt * f2[1];
                    acc[6] += wgt * f3[0]; acc[7] += wgt * f3[1];
                }
            } else {
                unsigned short p4[4];
#pragma unroll
                for (int u = 0; u < 4; ++u) p4[u] = *(const unsigned short*)(hp + (size_t)s4[u] * F);
#pragma unroll
                for (int u = 0; u < 4; ++u) {
                    float wgt = w4[u];
                    wsum += wgt;
                    floatx2 f0 = __builtin_amdgcn_cvt_pk_f32_fp8((int)p4[u], false);
                    acc[0] += wgt * f0[0]; acc[1] += wgt * f0[1];
                }
            }
        }
        for (; e < n_t; ++e) {
            int s0 = sIdx[wave][e];
            float wgt = sWgt[wave][e * H + hsel];
            wsum += wgt;
            if (H == 4) {
                uint2 p = *(const uint2*)(hp + (size_t)s0 * F);
                floatx2 f0 = __builtin_amdgcn_cvt_pk_f32_fp8(p.x, false);
                floatx2 f1 = __builtin_amdgcn_cvt_pk_f32_fp8(p.x, true);
                floatx2 f2 = __builtin_amdgcn_cvt_pk_f32_fp8(p.y, false);
                floatx2 f3 = __builtin_amdgcn_cvt_pk_f32_fp8(p.y, true);
                acc[0] += wgt * f0[0]; acc[1] += wgt * f0[1];
                acc[2] += wgt * f1[0]; acc[3] += wgt * f1[1];
                acc[4] += wgt * f2[0]; acc[5] += wgt * f2[1];
                acc[6] += wgt * f3[0]; acc[7] += wgt * f3[1];
            } else {
                unsigned short p = *(const unsigned short*)(hp + (size_t)s0 * F);
                floatx2 f0 = __builtin_amdgcn_cvt_pk_f32_fp8((int)p, false);
                acc[0] += wgt * f0[0]; acc[1] += wgt * f0[1];
            }
        }
    }

    float inv = 1.f / (wsum + 1e-16f);
    if (H == 4) {
        bfrag8 r;
#pragma unroll
        for (int k = 0; k < 8; ++k) {
            float o = acc[k] * inv + bias[lane * 8 + k];
            o = o > 0.f ? o : __expf(o) - 1.f;     // ELU
            r[k] = (__bf16)o;
        }
        *(bfrag8*)op = r;
    } else {
        bfrag2 r;
#pragma unroll
        for (int k = 0; k < 2; ++k) {
            float o = acc[k] * inv + bias[lane * 2 + k];
            o = o > 0.f ? o : __expf(o) - 1.f;
            r[k] = (__bf16)o;
        }
        *(bfrag2*)op = r;
    }
}

// ---------------- launch ----------------

extern "C" void kernel_launch(void* const* d_in, const int* in_sizes, int n_in,
                              void* d_out, int out_size, void* d_ws, size_t ws_size,
                              hipStream_t stream) {
    const float* x   = (const float*)d_in[0];
    const float* W1  = (const float*)d_in[1];
    const float* a1s = (const float*)d_in[2];
    const float* a1d = (const float*)d_in[3];
    const float* b1  = (const float*)d_in[4];
    const float* W2  = (const float*)d_in[5];
    const float* a2s = (const float*)d_in[6];
    const float* a2d = (const float*)d_in[7];
    const float* b2  = (const float*)d_in[8];
    const float* W3  = (const float*)d_in[9];
    const float* a3s = (const float*)d_in[10];
    const float* a3d = (const float*)d_in[11];
    const float* b3  = (const float*)d_in[12];
    const float* Wl  = (const float*)d_in[13];
    const float* bl  = (const float*)d_in[14];
    const float* Wr  = (const float*)d_in[15];
    const float* br  = (const float*)d_in[16];
    const int*   ei  = (const int*)d_in[17];
    const int E = in_sizes[17] / 2;
    const int* esrc = ei;
    const int* edst = ei + E;
    const int slots = E + N_NODES;
    float* out = (float*)d_out;

    char* w = (char*)d_ws;
    auto alloc = [&](size_t b) { char* p = w; w += (b + 255) & ~(size_t)255; return p; };
    __bf16* xb  = (__bf16*)alloc((size_t)M_PAD * 512 * 2);
    __bf16* hb  = (__bf16*)alloc((size_t)M_PAD * 512 * 2);
    __bf16* hb3 = (__bf16*)alloc((size_t)M_PAD * 128 * 2);
    unsigned char* Hi8 = (unsigned char*)alloc((size_t)M_PAD * 512);
    __bf16* W1T = (__bf16*)alloc(512 * 512 * 2);
    __bf16* W2T = (__bf16*)alloc(512 * 512 * 2);
    __bf16* W3T = (__bf16*)alloc(128 * 512 * 2);
    __bf16* WlT = (__bf16*)alloc(256 * 128 * 2);
    __bf16* WrT = (__bf16*)alloc(256 * 512 * 2);
    float* esp    = (float*)alloc((size_t)M_PAD * HEADS * 4);
    float* edp    = (float*)alloc((size_t)M_PAD * HEADS * 4);
    int*   deg    = (int*)alloc(N_NODES * 4);
    int*   rowptr = (int*)alloc((N_NODES + 1) * 4);
    int*   cursor = (int*)alloc(N_NODES * 4);
    int*   csr    = (int*)alloc((size_t)slots * 4);

    (void)hipMemsetAsync(deg, 0, N_NODES * sizeof(int), stream);

    const int sp_total = S0V + S1E + S2E + S3E + S4E + S5E + E;
    prep<<<(sp_total + 255) / 256, 256, 0, stream>>>(x, W1, W2, W3, Wl, Wr, edst, E,
                                                     xb, W1T, W2T, W3T, WlT, WrT, deg);
    scan_kernel<<<1, 1024, 0, stream>>>(deg, rowptr, cursor, N_NODES);

    const int scat_blocks = (E + N_NODES + 255) / 256;
    // layer 1 GEMM + CSR scatter (one dispatch)
    gemm1s<<<320 + scat_blocks, 256, 0, stream>>>(xb, W1T, Hi8, a1s, a1d, esp, edp,
                                                  esrc, edst, E, cursor, csr);
    gather_agg<4><<<M_PAD / 4, 256, 0, stream>>>(Hi8, esp, edp, rowptr, csr, b1, hb);
    // layer 2
    gemm_h<<<dim3(80, 4), 256, 0, stream>>>(hb, W2T, Hi8, 512, 512, 4,
                                            a2s, a2d, esp, edp);
    gather_agg<4><<<M_PAD / 4, 256, 0, stream>>>(Hi8, esp, edp, rowptr, csr, b2, hb);
    // layer 3 (H=1) + residual out = xb@WrT + br (one dispatch)
    gemm3r<<<400, 256, 0, stream>>>(hb, W3T, Hi8, a3s, a3d, esp, edp,
                                    xb, WrT, br, out);
    gather_agg<1><<<M_PAD / 4, 256, 0, stream>>>(Hi8, esp, edp, rowptr, csr, b3, hb3);
    // final: out += hb3@WlT + bl (K=128)
    gemm_acc<<<dim3(80, 4), 256, 0, stream>>>(hb3, WlT, out, bl);
}